// Round 11
// baseline (541.233 us; speedup 1.0000x reference)
//
#include <hip/hip_runtime.h>
#include <math.h>

#define Bc   160
#define Lc   196
#define Cc   768
#define Dc   512
#define NVc  196
#define Tc   87
#define FRc  10
#define DMc  384
#define DSc  48
#define LROW 196
#define ALPHAc 0.3f
#define BETAc  0.05f
#define GAMMAc 0.05f
#define EPSc   1e-5f

typedef __attribute__((ext_vector_type(8))) short short8v;
typedef __attribute__((ext_vector_type(4))) short short4v;
typedef __attribute__((ext_vector_type(4))) float f32x4;

__device__ __forceinline__ short f2bf(float f) {
    unsigned u = __builtin_bit_cast(unsigned, f);
    u = (u + 0x7FFFu + ((u >> 16) & 1u)) >> 16;
    return (short)u;
}
__device__ __forceinline__ float bf2f(short s) {
    unsigned u = ((unsigned)(unsigned short)s) << 16;
    return __builtin_bit_cast(float, u);
}

__device__ __forceinline__ void gload16(const void* g, void* l) {
    using GP = const __attribute__((address_space(1))) unsigned int*;
    using LP = __attribute__((address_space(3))) unsigned int*;
    __builtin_amdgcn_global_load_lds((GP)(uintptr_t)g, (LP)(uintptr_t)l, 16, 0, 0);
}

// ============================================================
// bf16 MFMA GEMM, 128x128 tile (as round 10).
// ============================================================
template<int BIAS, int ACT, int OUT, int STORE, int ADDT,
         bool ASCALE, bool RSUM, bool CSCALE, bool MULP, int BMODE, bool SWZ, bool FLAT,
         bool TSTORE>
__global__ __launch_bounds__(256) void mgemm(
    const short* __restrict__ A, long sA,
    const void* __restrict__ Bp, long sB, int ldB, int Klim,
    float* __restrict__ Cf, long sCf,
    short* __restrict__ Cb, long sCb, int ldC,
    float* __restrict__ Rf, long sRf,
    const void* __restrict__ Addp, long sAdd,
    const float* __restrict__ scalePtr,
    const float* __restrict__ biasR, const float* __restrict__ biasC,
    const float* __restrict__ ascale, const float* __restrict__ wcol,
    const float* __restrict__ csc, const float* __restrict__ mulp,
    int M, int N, int K, int nI, int nJ, float outScale)
{
    constexpr bool DEEP = (BMODE == 0) && !ASCALE;
    constexpr int LDSN = DEEP ? 24576 : 16384;
    constexpr int BOFF = DEEP ? 12288 : 8192;
    __shared__ short smem[LDSN];
    int b, iT, jT;
    if (FLAT) {
        b = 0;
        int id = blockIdx.x;
        int nI8 = (nI >> 3) << 3;
        int main_ = nI8 * nJ;
        if (id < main_) { int xx = id & 7; int q = id >> 3; jT = q % nJ; iT = (q / nJ) * 8 + xx; }
        else { int id2 = id - main_; iT = nI8 + id2 / nJ; jT = id2 % nJ; }
    } else {
        const int tiles = nI * nJ;
        int t;
        if (SWZ) { int id = blockIdx.x; b = ((id >> 3) / tiles) * 8 + (id & 7); t = (id >> 3) % tiles; }
        else     { int id = blockIdx.x; b = id / tiles; t = id % tiles; }
        iT = t / nJ; jT = t % nJ;
    }
    const int i0 = iT * 128, j0 = jT * 128;
    const int tid = threadIdx.x;
    const int wl = tid & 63, w = tid >> 6;
    const int wr = (w >> 1) * 64, wc = (w & 1) * 64;
    const int lr = wl & 15;
    const int kgl = (((wl >> 4) ^ (lr & 3) ^ ((lr >> 2) & 3)) * 8);
    const int sl8 = (((tid & 3) ^ ((tid >> 2) & 3) ^ ((tid >> 4) & 3)) * 8);
    const int grow = w * 16 + (wl >> 2);
    const int srow = tid >> 2;
    const short* Ab = A + (FLAT ? 0L : (long)b * sA);

    f32x4 acc[4][4] = {};

    // ---- staging helpers ----
    auto GLA = [&](short* Asb, int k0) {
        #pragma unroll
        for (int h = 0; h < 2; ++h) {
            int gi = i0 + h * 64 + grow; if (gi > M - 1) gi = M - 1;
            gload16(Ab + (long)gi * K + k0 + sl8, Asb + h * 2048 + w * 512);
        }
    };
    auto GLB = [&](short* Bsb, int k0) {
        const short* Bb = (const short*)Bp + (FLAT ? 0L : (long)b * sB);
        #pragma unroll
        for (int h = 0; h < 2; ++h) {
            int gj = j0 + h * 64 + grow; if (gj > N - 1) gj = N - 1;
            gload16(Bb + (long)gj * K + k0 + sl8, Bsb + h * 2048 + w * 512);
        }
    };
    auto LDA_R = [&](int k0, short8v& a0, short8v& a1) {
        {
            int gi = i0 + srow; if (gi > M - 1) gi = M - 1;
            short8v av = *(const short8v*)(Ab + (long)gi * K + k0 + (tid & 3) * 8);
            int bb = FLAT ? (gi / LROW) : b;
            const float* asb = ascale + (long)bb * K + k0 + (tid & 3) * 8;
            #pragma unroll
            for (int e = 0; e < 8; ++e) av[e] = f2bf(bf2f(av[e]) * asb[e]);
            a0 = av;
        }
        {
            int gi = i0 + srow + 64; if (gi > M - 1) gi = M - 1;
            short8v av = *(const short8v*)(Ab + (long)gi * K + k0 + (tid & 3) * 8);
            int bb = FLAT ? (gi / LROW) : b;
            const float* asb = ascale + (long)bb * K + k0 + (tid & 3) * 8;
            #pragma unroll
            for (int e = 0; e < 8; ++e) av[e] = f2bf(bf2f(av[e]) * asb[e]);
            a1 = av;
        }
    };
    auto WRA_R = [&](short* Asb, short8v a0, short8v a1) {
        *(short8v*)&Asb[srow * 32 + sl8] = a0;
        *(short8v*)&Asb[(srow + 64) * 32 + sl8] = a1;
    };
    auto LDB1_R = [&](int k0, short8v& b0, short8v& b1) {
        const short* Bb = (const short*)Bp + (long)b * sB;
        {
            int kk = tid >> 4, jg = tid & 15;
            int gk = k0 + kk, gj = j0 + jg * 8;
            short8v bv = {};
            if (gk < Klim && gj < N) bv = *(const short8v*)(Bb + (long)gk * ldB + gj);
            b0 = bv;
        }
        {
            int idx = tid + 256;
            int kk = idx >> 4, jg = idx & 15;
            int gk = k0 + kk, gj = j0 + jg * 8;
            short8v bv = {};
            if (gk < Klim && gj < N) bv = *(const short8v*)(Bb + (long)gk * ldB + gj);
            b1 = bv;
        }
    };
    auto WRB1_R = [&](short* Bsb, short8v b0, short8v b1) {
        {
            int kk = tid >> 4, jg = tid & 15;
            #pragma unroll
            for (int e = 0; e < 8; ++e) {
                int row = jg * 8 + e;
                int slot = (kk >> 3) ^ (row & 3) ^ ((row >> 2) & 3);
                Bsb[row * 32 + slot * 8 + (kk & 7)] = b0[e];
            }
        }
        {
            int idx = tid + 256;
            int kk = idx >> 4, jg = idx & 15;
            #pragma unroll
            for (int e = 0; e < 8; ++e) {
                int row = jg * 8 + e;
                int slot = (kk >> 3) ^ (row & 3) ^ ((row >> 2) & 3);
                Bsb[row * 32 + slot * 8 + (kk & 7)] = b1[e];
            }
        }
    };
    auto LDB2_R = [&](int k0, short8v& b0, short8v& b1) {
        const float* Bb = (const float*)Bp + (long)b * sB;
        {
            int gj = j0 + srow;
            short8v bv = {};
            if (gj < N) {
                const float* p = Bb + (long)gj * K + k0 + (tid & 3) * 8;
                float4 lo = *(const float4*)p, hi = *(const float4*)(p + 4);
                bv[0] = f2bf(lo.x); bv[1] = f2bf(lo.y); bv[2] = f2bf(lo.z); bv[3] = f2bf(lo.w);
                bv[4] = f2bf(hi.x); bv[5] = f2bf(hi.y); bv[6] = f2bf(hi.z); bv[7] = f2bf(hi.w);
            }
            b0 = bv;
        }
        {
            int gj = j0 + srow + 64;
            short8v bv = {};
            if (gj < N) {
                const float* p = Bb + (long)gj * K + k0 + (tid & 3) * 8;
                float4 lo = *(const float4*)p, hi = *(const float4*)(p + 4);
                bv[0] = f2bf(lo.x); bv[1] = f2bf(lo.y); bv[2] = f2bf(lo.z); bv[3] = f2bf(lo.w);
                bv[4] = f2bf(hi.x); bv[5] = f2bf(hi.y); bv[6] = f2bf(hi.z); bv[7] = f2bf(hi.w);
            }
            b1 = bv;
        }
    };
    auto WRB2_R = [&](short* Bsb, short8v b0, short8v b1) {
        *(short8v*)&Bsb[srow * 32 + sl8] = b0;
        *(short8v*)&Bsb[(srow + 64) * 32 + sl8] = b1;
    };

    auto COMPUTE = [&](const short* as, const short* bs) {
        short8v af[4], bfv[4];
        #pragma unroll
        for (int m = 0; m < 4; ++m) af[m]  = *(const short8v*)&as[(wr + m * 16 + lr) * 32 + kgl];
        #pragma unroll
        for (int n = 0; n < 4; ++n) bfv[n] = *(const short8v*)&bs[(wc + n * 16 + lr) * 32 + kgl];
        #pragma unroll
        for (int m = 0; m < 4; ++m)
            #pragma unroll
            for (int n = 0; n < 4; ++n)
                acc[m][n] = __builtin_amdgcn_mfma_f32_16x16x32_bf16(af[m], bfv[n], acc[m][n], 0, 0, 0);
    };

    const int nt = K >> 5;
    if (DEEP) {
        GLA(smem, 0); GLB(smem + BOFF, 0);
        if (nt > 1) { GLA(smem + 4096, 32); GLB(smem + BOFF + 4096, 32); }
        for (int tt = 0; tt < nt; ++tt) {
            if (tt + 1 < nt) asm volatile("s_waitcnt vmcnt(4)" ::: "memory");
            else             asm volatile("s_waitcnt vmcnt(0)" ::: "memory");
            __builtin_amdgcn_s_barrier();
            __builtin_amdgcn_sched_barrier(0);
            if (tt + 2 < nt) {
                int nb = (tt + 2) % 3;
                GLA(smem + nb * 4096, (tt + 2) * 32);
                GLB(smem + BOFF + nb * 4096, (tt + 2) * 32);
            }
            int cb = tt % 3;
            COMPUTE(smem + cb * 4096, smem + BOFF + cb * 4096);
        }
    } else {
        short8v rA0{}, rA1{}, rB0{}, rB1{};
        if (ASCALE) { LDA_R(0, rA0, rA1); WRA_R(smem, rA0, rA1); }
        else GLA(smem, 0);
        if (BMODE == 1) { LDB1_R(0, rB0, rB1); WRB1_R(smem + BOFF, rB0, rB1); }
        else if (BMODE == 2) { LDB2_R(0, rB0, rB1); WRB2_R(smem + BOFF, rB0, rB1); }
        else GLB(smem + BOFF, 0);
        if (nt > 1) {
            if (ASCALE) LDA_R(32, rA0, rA1);
            if (BMODE == 1) LDB1_R(32, rB0, rB1);
            else if (BMODE == 2) LDB2_R(32, rB0, rB1);
        }
        for (int tt = 0; tt < nt; ++tt) {
            __syncthreads();
            if (tt + 1 < nt) {
                short* ab  = smem + ((tt + 1) & 1) * 4096;
                short* bb2 = smem + BOFF + ((tt + 1) & 1) * 4096;
                if (ASCALE) WRA_R(ab, rA0, rA1); else GLA(ab, (tt + 1) * 32);
                if (BMODE == 1) WRB1_R(bb2, rB0, rB1);
                else if (BMODE == 2) WRB2_R(bb2, rB0, rB1);
                else GLB(bb2, (tt + 1) * 32);
            }
            short8v nA0 = rA0, nA1 = rA1, nB0 = rB0, nB1 = rB1;
            if (tt + 2 < nt) {
                if (ASCALE) LDA_R((tt + 2) * 32, nA0, nA1);
                if (BMODE == 1) LDB1_R((tt + 2) * 32, nB0, nB1);
                else if (BMODE == 2) LDB2_R((tt + 2) * 32, nB0, nB1);
            }
            COMPUTE(smem + (tt & 1) * 4096, smem + BOFF + (tt & 1) * 4096);
            rA0 = nA0; rA1 = nA1; rB0 = nB0; rB1 = nB1;
        }
    }

    const int colbase = j0 + wc;
    const int rowbase = i0 + wr;
    float scale = 1.f;
    if (ADDT) scale = scalePtr ? scalePtr[0] : 1.f;
    const int bA = FLAT ? (i0 / LROW) : 0;
    const bool straddle = FLAT && (((i0 + 127) / LROW) != bA);

    if (OUT == 0 && TSTORE) {
        float rsum[4] = {0.f, 0.f, 0.f, 0.f};
        float rsum2[4] = {0.f, 0.f, 0.f, 0.f};
        __syncthreads();
        #pragma unroll
        for (int n = 0; n < 4; ++n) {
            int col = wc + n * 16 + lr;
            int j = j0 + col;
            int jc = j < N ? j : N - 1;
            #pragma unroll
            for (int m = 0; m < 4; ++m) {
                #pragma unroll
                for (int r = 0; r < 4; ++r) {
                    int row = wr + m * 16 + (wl >> 4) * 4 + r;
                    int i = i0 + row;
                    int ic = i < M ? i : M - 1;
                    float v = acc[m][n][r];
                    if (BIAS == 1) v += biasR[ic];
                    else if (BIAS == 2) v += biasC[jc];
                    else if (BIAS == 3) v = v * biasR[jc] + biasC[jc];
                    if (ACT == 1) v = fmaxf(v, 0.f);
                    else if (ACT == 2) v = 1.f / (1.f + expf(-v));
                    else if (ACT == 3) v = 1.f + 1.f / (1.f + expf(-v));
                    if (CSCALE) v *= csc[jc];
                    if (MULP) v *= mulp[(long)ic * N + jc];
                    smem[row * 128 + col] = f2bf(v);
                    if (RSUM && j < N && i < M) {
                        if (FLAT && (i / LROW) != bA) rsum2[n] += v;
                        else rsum[n] += v;
                    }
                }
            }
        }
        if (RSUM) {
            #pragma unroll
            for (int n = 0; n < 4; ++n) {
                int j = colbase + n * 16 + lr;
                float s = rsum[n];
                s += __shfl_xor(s, 16, 64);
                s += __shfl_xor(s, 32, 64);
                float s2 = 0.f;
                if (FLAT && straddle) {
                    s2 = rsum2[n];
                    s2 += __shfl_xor(s2, 16, 64);
                    s2 += __shfl_xor(s2, 32, 64);
                }
                if ((wl >> 4) == 0 && j < N) {
                    atomicAdd(&Rf[(long)bA * sRf + (FLAT ? 0 : (long)b * sRf) + j], s * outScale);
                    if (FLAT && straddle)
                        atomicAdd(&Rf[(long)(bA + 1) * sRf + j], s2 * outScale);
                }
            }
        }
        __syncthreads();
        #pragma unroll
        for (int p = 0; p < 8; ++p) {
            int row = (tid >> 4) + p * 16;
            int i = i0 + row;
            int c8 = (tid & 15) * 8;
            int j = j0 + c8;
            if (i < M && j < ldC) {
                short8v sv = *(const short8v*)&smem[row * 128 + c8];
                if (ADDT == 2) {
                    const short* ap = (const short*)Addp + (long)b * sAdd + (long)i * N + j;
                    short8v av = *(const short8v*)ap;
                    #pragma unroll
                    for (int e = 0; e < 8; ++e) sv[e] = f2bf(bf2f(av[e]) + scale * bf2f(sv[e]));
                } else if (ADDT == 1) {
                    const float* ap = (const float*)Addp + (long)b * sAdd + (long)i * N + j;
                    f32x4 lo = *(const f32x4*)ap, hi = *(const f32x4*)(ap + 4);
                    #pragma unroll
                    for (int e = 0; e < 4; ++e) sv[e] = f2bf(lo[e] + scale * bf2f(sv[e]));
                    #pragma unroll
                    for (int e = 0; e < 4; ++e) sv[e + 4] = f2bf(hi[e] + scale * bf2f(sv[e + 4]));
                }
                *(short8v*)&Cb[(long)b * sCb + (long)i * ldC + j] = sv;
            }
        }
    } else if (OUT == 0) {
        float rsum[4] = {0.f, 0.f, 0.f, 0.f};
        float rsum2[4] = {0.f, 0.f, 0.f, 0.f};
        #pragma unroll
        for (int n = 0; n < 4; ++n) {
            int j = colbase + n * 16 + lr;
            if (j >= N) continue;
            #pragma unroll
            for (int m = 0; m < 4; ++m) {
                #pragma unroll
                for (int r = 0; r < 4; ++r) {
                    int i = rowbase + m * 16 + (wl >> 4) * 4 + r;
                    if (i >= M) continue;
                    float v = acc[m][n][r];
                    if (BIAS == 1) v += biasR[i];
                    else if (BIAS == 2) v += biasC[j];
                    else if (BIAS == 3) v = v * biasR[j] + biasC[j];
                    if (ACT == 1) v = fmaxf(v, 0.f);
                    else if (ACT == 2) v = 1.f / (1.f + expf(-v));
                    else if (ACT == 3) v = 1.f + 1.f / (1.f + expf(-v));
                    if (CSCALE) v *= csc[j];
                    if (MULP) v *= mulp[(long)i * N + j];
                    if (ADDT == 1) v = ((const float*)Addp)[(long)b * sAdd + (long)i * N + j] + scale * v;
                    else if (ADDT == 2) v = bf2f(((const short*)Addp)[(long)b * sAdd + (long)i * N + j]) + scale * v;
                    if (STORE & 1) Cf[(long)b * sCf + (long)i * N + j] = v;
                    if (STORE & 2) Cb[(long)b * sCb + (long)i * ldC + j] = f2bf(v);
                    if (RSUM) {
                        if (FLAT && (i / LROW) != bA) rsum2[n] += v;
                        else rsum[n] += v;
                    }
                }
            }
        }
        if (RSUM) {
            #pragma unroll
            for (int n = 0; n < 4; ++n) {
                int j = colbase + n * 16 + lr;
                float s = rsum[n];
                s += __shfl_xor(s, 16, 64);
                s += __shfl_xor(s, 32, 64);
                float s2 = 0.f;
                if (FLAT && straddle) {
                    s2 = rsum2[n];
                    s2 += __shfl_xor(s2, 16, 64);
                    s2 += __shfl_xor(s2, 32, 64);
                }
                if ((wl >> 4) == 0 && j < N) {
                    atomicAdd(&Rf[(long)bA * sRf + (FLAT ? 0 : (long)b * sRf) + j], s * outScale);
                    if (FLAT && straddle)
                        atomicAdd(&Rf[(long)(bA + 1) * sRf + j], s2 * outScale);
                }
            }
        }
    } else if (OUT == 1) {
        #pragma unroll
        for (int n = 0; n < 4; ++n) {
            int j = colbase + n * 16 + lr;
            if (j < N) {
                float s = 0.f, s2 = 0.f;
                #pragma unroll
                for (int m = 0; m < 4; ++m)
                    #pragma unroll
                    for (int r = 0; r < 4; ++r) {
                        int i = rowbase + m * 16 + (wl >> 4) * 4 + r;
                        if (i >= M) continue;
                        float v = acc[m][n][r];
                        if (BIAS == 2) v += biasC[j];
                        if (ACT == 1) v = fmaxf(v, 0.f);
                        if (FLAT && (i / LROW) != bA) s2 += v; else s += v;
                    }
                s += __shfl_xor(s, 16, 64);
                s += __shfl_xor(s, 32, 64);
                if (FLAT && straddle) {
                    s2 += __shfl_xor(s2, 16, 64);
                    s2 += __shfl_xor(s2, 32, 64);
                }
                if ((wl >> 4) == 0) {
                    atomicAdd(&Cf[(long)(FLAT ? bA : b) * sCf + j], s * outScale);
                    if (FLAT && straddle)
                        atomicAdd(&Cf[(long)(bA + 1) * sCf + j], s2 * outScale);
                }
            }
        }
    } else {
        #pragma unroll
        for (int m = 0; m < 4; ++m) {
            #pragma unroll
            for (int r = 0; r < 4; ++r) {
                int i = rowbase + m * 16 + (wl >> 4) * 4 + r;
                int bw = FLAT ? (i < M ? i / LROW : 0) : b;
                float s = 0.f;
                #pragma unroll
                for (int n = 0; n < 4; ++n) {
                    int j = colbase + n * 16 + lr;
                    if (j >= N) continue;
                    float v = acc[m][n][r];
                    if (BIAS == 2) v += biasC[j];
                    if (ACT == 1) v = fmaxf(v, 0.f);
                    s += v * wcol[(long)bw * N + j];
                }
                s += __shfl_xor(s, 1, 64);
                s += __shfl_xor(s, 2, 64);
                s += __shfl_xor(s, 4, 64);
                s += __shfl_xor(s, 8, 64);
                if (lr == 0 && i < M)
                    atomicAdd(&Cf[(FLAT ? (long)i : (long)b * sCf + i)], s * outScale);
            }
        }
    }
}

// ============================================================
// 256x256 big-tile GEMM for vq1m: out[b,c] += mean_l relu(A . B^T + bias)
// 512 threads, 8 waves (2 row-groups x 4 col-groups), per-wave 128x64.
// A [M][K] flat bf16, B [N][K] bf16, K%32==0, N%256==0.
// ============================================================
__global__ __launch_bounds__(512) void mgemm_vq1m(
    const short* __restrict__ A, const short* __restrict__ Bw,
    const float* __restrict__ biasC, float* __restrict__ Rf,
    int M, int N, int K, int nI, int nJ, float outScale)
{
    __shared__ short smem[32768];   // [2][16384]: per buf A 256x32 | B 256x32
    int iT, jT;
    {
        int id = blockIdx.x;
        int nI8 = (nI >> 3) << 3;
        int main_ = nI8 * nJ;
        if (id < main_) { int xx = id & 7; int q = id >> 3; jT = q % nJ; iT = (q / nJ) * 8 + xx; }
        else { int id2 = id - main_; iT = nI8 + id2 / nJ; jT = id2 % nJ; }
    }
    const int i0 = iT * 256, j0 = jT * 256;
    const int tid = threadIdx.x;
    const int wl = tid & 63, w = tid >> 6;        // 8 waves
    const int wr = (w >> 2) * 128, wc = (w & 3) * 64;
    const int lr = wl & 15;
    const int kgrp = wl >> 4;
    const int kgl = ((kgrp ^ (lr & 3) ^ ((lr >> 2) & 3)) * 8);
    const int sl8 = (((wl & 3) ^ ((wl >> 2) & 3) ^ ((wl >> 4) & 3)) * 8);
    const int grow = w * 16 + (wl >> 2);          // 0..127

    f32x4 acc[8][4] = {};

    auto STAGE = [&](int bufi, int k0) {
        short* Asb = smem + bufi * 16384;
        short* Bsb = Asb + 8192;
        #pragma unroll
        for (int h = 0; h < 2; ++h) {
            int gi = i0 + h * 128 + grow; if (gi > M - 1) gi = M - 1;
            gload16(A + (long)gi * K + k0 + sl8, Asb + h * 4096 + w * 512);
            int gj = j0 + h * 128 + grow;         // N multiple of 256: in range
            gload16(Bw + (long)gj * K + k0 + sl8, Bsb + h * 4096 + w * 512);
        }
    };

    auto COMPUTE = [&](int bufi) {
        const short* as = smem + bufi * 16384;
        const short* bs = as + 8192;
        short8v af[8], bfv[4];
        #pragma unroll
        for (int m = 0; m < 8; ++m) af[m]  = *(const short8v*)&as[(wr + m * 16 + lr) * 32 + kgl];
        #pragma unroll
        for (int n = 0; n < 4; ++n) bfv[n] = *(const short8v*)&bs[(wc + n * 16 + lr) * 32 + kgl];
        #pragma unroll
        for (int m = 0; m < 8; ++m)
            #pragma unroll
            for (int n = 0; n < 4; ++n)
                acc[m][n] = __builtin_amdgcn_mfma_f32_16x16x32_bf16(af[m], bfv[n], acc[m][n], 0, 0, 0);
    };

    const int nt = K >> 5;
    STAGE(0, 0);
    for (int tt = 0; tt < nt; ++tt) {
        __syncthreads();
        if (tt + 1 < nt) STAGE((tt + 1) & 1, (tt + 1) * 32);
        COMPUTE(tt & 1);
    }

    const int bA = i0 / LROW;
    int lastRow = i0 + 255; if (lastRow > M - 1) lastRow = M - 1;
    const bool straddle = (lastRow / LROW) != bA;

    #pragma unroll
    for (int n = 0; n < 4; ++n) {
        int j = j0 + wc + n * 16 + lr;
        float s = 0.f, s2 = 0.f;
        #pragma unroll
        for (int m = 0; m < 8; ++m) {
            #pragma unroll
            for (int r = 0; r < 4; ++r) {
                int i = i0 + wr + m * 16 + kgrp * 4 + r;
                if (i >= M) continue;
                float v = acc[m][n][r] + biasC[j];
                v = fmaxf(v, 0.f);
                if ((i / LROW) != bA) s2 += v; else s += v;
            }
        }
        s += __shfl_xor(s, 16, 64);
        s += __shfl_xor(s, 32, 64);
        if (straddle) {
            s2 += __shfl_xor(s2, 16, 64);
            s2 += __shfl_xor(s2, 32, 64);
        }
        if (kgrp == 0) {
            atomicAdd(&Rf[(long)bA * N + j], s * outScale);
            if (straddle)
                atomicAdd(&Rf[(long)(bA + 1) * N + j], s2 * outScale);
        }
    }
}

// wide f32 -> bf16 convert (8 elems/thread)
__global__ __launch_bounds__(256) void k_cvt_vis(const float* __restrict__ in,
                                                 short* __restrict__ out, long n)
{
    long i = ((long)blockIdx.x * 256 + threadIdx.x) * 8;
    if (i >= n) return;
    f32x4 lo = *(const f32x4*)(in + i), hi = *(const f32x4*)(in + i + 4);
    short8v s;
    s[0] = f2bf(lo[0]); s[1] = f2bf(lo[1]); s[2] = f2bf(lo[2]); s[3] = f2bf(lo[3]);
    s[4] = f2bf(hi[0]); s[5] = f2bf(hi[1]); s[6] = f2bf(hi[2]); s[7] = f2bf(hi[3]);
    *(short8v*)(out + i) = s;
}

// all weight conversions in one kernel
__global__ void k_cvt_weights(
    const float* __restrict__ my_tok, const float* __restrict__ conv_w,
    const float* __restrict__ a1_w, const float* __restrict__ v1_w,
    const float* __restrict__ bt_w, const float* __restrict__ vc_w,
    const float* __restrict__ v2_w, const float* __restrict__ a2_w,
    const float* __restrict__ down_w, const float* __restrict__ fc_w,
    const float* __restrict__ up_w,
    short* __restrict__ mytok_bf, short* __restrict__ wconv,
    short* __restrict__ wa1, short* __restrict__ wv1,
    short* __restrict__ wbt, short* __restrict__ wvc,
    short* __restrict__ wv2, short* __restrict__ wa2,
    short* __restrict__ wdown, short* __restrict__ wfc, short* __restrict__ wup)
{
    long idx = (long)blockIdx.x * 256 + threadIdx.x;
    if (idx < 66816)  { mytok_bf[idx] = f2bf(my_tok[idx]); return; }  idx -= 66816;
    if (idx < 100352) { wconv[idx] = f2bf(conv_w[idx]); return; }     idx -= 100352;
    if (idx < 589824) { wa1[idx] = f2bf(a1_w[idx]); return; }         idx -= 589824;
    if (idx < 589824) { wv1[idx] = f2bf(v1_w[idx]); return; }         idx -= 589824;
    if (idx < 294912) { wbt[idx] = f2bf(bt_w[idx]); return; }         idx -= 294912;
    if (idx < 294912) { wvc[idx] = f2bf(vc_w[idx]); return; }         idx -= 294912;
    if (idx < 294912) { wv2[idx] = f2bf(v2_w[idx]); return; }         idx -= 294912;
    if (idx < 294912) { wa2[idx] = f2bf(a2_w[idx]); return; }         idx -= 294912;
    if (idx < 36864)  { wdown[idx] = f2bf(down_w[idx]); return; }     idx -= 36864;
    if (idx < 172032) { int r = (int)(idx / 224), c = (int)(idx % 224);
                        wfc[idx] = (c < 196) ? f2bf(fc_w[(long)r * 196 + c]) : (short)0; return; }
    idx -= 172032;
    if (idx < 49152)  { int r = (int)(idx / 64), c = (int)(idx % 64);
                        wup[idx] = (c < 48) ? f2bf(up_w[(long)r * 48 + c]) : (short)0; }
}

// bn1 + bn2 affine precompute
__global__ void k_prep(const float* g1, const float* b1, const float* m1, const float* v1,
                       const float* g2, const float* b2, const float* m2, const float* v2,
                       float* scl1, float* sft1, float* scl2, float* sft2)
{
    int j = threadIdx.x;
    if (j < DSc) { float r = rsqrtf(v1[j] + EPSc) * g1[j]; scl1[j] = r; sft1[j] = b1[j] - m1[j] * r; }
    if (j < Cc)  { float r = rsqrtf(v2[j] + EPSc) * g2[j]; scl2[j] = r; sft2[j] = b2[j] - m2[j] * r; }
}

// xt[b,l,c] = x[b,c,l] -> bf16, 64c x 32l tile, short4 stores
__global__ __launch_bounds__(256) void k_transpose(const float* __restrict__ x, short* __restrict__ xtb)
{
    __shared__ float tile[64][33];
    int b = blockIdx.z;
    int c0 = blockIdx.y * 64, l0 = blockIdx.x * 32;
    int tx = threadIdx.x & 31, ty = threadIdx.x >> 5;  // 32 x 8
    #pragma unroll
    for (int k = 0; k < 8; ++k) {
        int c = c0 + ty + 8 * k, l = l0 + tx;
        tile[ty + 8 * k][tx] = (l < Lc) ? x[((long)b * Cc + c) * Lc + l] : 0.f;
    }
    __syncthreads();
    int cg = threadIdx.x & 15, lw = threadIdx.x >> 4;  // 16 c-groups x 16 l
    #pragma unroll
    for (int p = 0; p < 2; ++p) {
        int l = l0 + lw + p * 16;
        if (l >= Lc) continue;
        int c = c0 + cg * 4;
        short4v sv;
        #pragma unroll
        for (int e = 0; e < 4; ++e) sv[e] = f2bf(tile[cg * 4 + e][lw + p * 16]);
        *(short4v*)(xtb + ((long)b * Lc + l) * Cc + c) = sv;
    }
}

// audio_bf + temporal gate, one block per b
__global__ __launch_bounds__(256) void k_audio_fin(
    const float* __restrict__ audio, short* __restrict__ audio_bf,
    const float* __restrict__ tg_w, const float* __restrict__ tg_b,
    float* __restrict__ tempv, float* __restrict__ outTemp)
{
    __shared__ float red[256];
    int b = blockIdx.x, tid = threadIdx.x;
    float part = 0.f;
    #pragma unroll
    for (int q = 0; q < 3; ++q) {
        int c = tid + q * 256;
        float a = audio[(long)b * Cc + c];
        audio_bf[(long)b * Cc + c] = f2bf(a);
        part += a * tg_w[c];
    }
    red[tid] = part; __syncthreads();
    for (int s = 128; s > 0; s >>= 1) { if (tid < s) red[tid] += red[tid + s]; __syncthreads(); }
    if (tid == 0) {
        float t = 1.f / (1.f + expf(-(red[0] + tg_b[0])));
        tempv[b] = t; outTemp[b] = t;
    }
}

// wave-per-row softmax: f32 rows (ld n) -> bf16 rows (ld ldo, zero pad)
__global__ __launch_bounds__(256) void k_softmax_w(const float* __restrict__ in,
                                                   short* __restrict__ out,
                                                   int n, int ldo, int rows)
{
    int r = blockIdx.x * 4 + (threadIdx.x >> 6);
    int lane = threadIdx.x & 63;
    if (r >= rows) return;
    const float* row = in + (long)r * n;
    float v[4];
    float mx = -INFINITY;
    #pragma unroll
    for (int q = 0; q < 4; ++q) {
        int c = lane + q * 64;
        v[q] = (c < n) ? row[c] : -INFINITY;
        mx = fmaxf(mx, v[q]);
    }
    #pragma unroll
    for (int off = 32; off > 0; off >>= 1) mx = fmaxf(mx, __shfl_xor(mx, off, 64));
    float sum = 0.f;
    #pragma unroll
    for (int q = 0; q < 4; ++q) {
        int c = lane + q * 64;
        float e = (c < n) ? expf(v[q] - mx) : 0.f;
        v[q] = e; sum += e;
    }
    #pragma unroll
    for (int off = 32; off > 0; off >>= 1) sum += __shfl_xor(sum, off, 64);
    float inv = 1.0f / sum;
    #pragma unroll
    for (int q = 0; q < 4; ++q) {
        int c = lane + q * 64;
        if (c < ldo) out[(long)r * ldo + c] = (c < n) ? f2bf(v[q] * inv) : (short)0;
    }
}

__global__ __launch_bounds__(256) void k_spatial(const float* __restrict__ stmp,
                                                 const float* __restrict__ vs_b,
                                                 float* __restrict__ ssig,
                                                 float* __restrict__ spat)
{
    __shared__ float red[256];
    int b = blockIdx.x, tid = threadIdx.x;
    float t = -INFINITY;
    if (tid < Lc) {
        float v = stmp[(long)b * Lc + tid] + vs_b[0];
        ssig[(long)b * Lc + tid] = 1.f / (1.f + expf(-v));
        t = tanhf(v);
    }
    red[tid] = t; __syncthreads();
    for (int s = 128; s > 0; s >>= 1) { if (tid < s) red[tid] = fmaxf(red[tid], red[tid + s]); __syncthreads(); }
    float mx = red[0]; __syncthreads();
    float e = (tid < Lc) ? expf(t - mx) : 0.f;
    red[tid] = e; __syncthreads();
    for (int s = 128; s > 0; s >>= 1) { if (tid < s) red[tid] += red[tid + s]; __syncthreads(); }
    if (tid < Lc) spat[(long)b * Lc + tid] = e / red[0];
}

// x6 = LN( bf16(xt) * factor ) -> bf16, in place; one wave per row
__global__ __launch_bounds__(256) void k_ln_factor(
    short* __restrict__ xt, const float* __restrict__ chp1,
    const float* __restrict__ ssig, const float* __restrict__ tmp_,
    const float* __restrict__ g, const float* __restrict__ be)
{
    long r = (long)blockIdx.x * 4 + (threadIdx.x >> 6);
    int lane = threadIdx.x & 63;
    int b = (int)(r / Lc);
    float rowterm = BETAc * ssig[r] + GAMMAc * tmp_[b] + (1.0f - ALPHAc);
    float v[12];
    #pragma unroll
    for (int q = 0; q < 3; ++q) {
        int c = lane * 4 + q * 256;
        short4v sv = *(const short4v*)(xt + r * Cc + c);
        f32x4 ch = *(const f32x4*)(chp1 + (long)b * Cc + c);
        #pragma unroll
        for (int e = 0; e < 4; ++e)
            v[q * 4 + e] = bf2f(sv[e]) * (ALPHAc * (ch[e] - 1.0f) + rowterm);
    }
    float s = 0.f;
    #pragma unroll
    for (int e = 0; e < 12; ++e) s += v[e];
    #pragma unroll
    for (int off = 32; off > 0; off >>= 1) s += __shfl_xor(s, off, 64);
    float mean = s * (1.0f / Cc);
    float var = 0.f;
    #pragma unroll
    for (int e = 0; e < 12; ++e) { float d = v[e] - mean; var += d * d; }
    #pragma unroll
    for (int off = 32; off > 0; off >>= 1) var += __shfl_xor(var, off, 64);
    float rs = rsqrtf(var * (1.0f / Cc) + EPSc);
    #pragma unroll
    for (int q = 0; q < 3; ++q) {
        int c = lane * 4 + q * 256;
        f32x4 gv = *(const f32x4*)(g + c);
        f32x4 bv = *(const f32x4*)(be + c);
        short4v sv;
        #pragma unroll
        for (int e = 0; e < 4; ++e)
            sv[e] = f2bf((v[q * 4 + e] - mean) * rs * gv[e] + bv[e]);
        *(short4v*)(xt + r * Cc + c) = sv;
    }
}

// LN(lnp) -> *gate -> transposed store out[b,c,l]; bf16 LDS tile, wave stats
__global__ __launch_bounds__(256) void k_final(
    const short* __restrict__ o,
    const float* __restrict__ lng, const float* __restrict__ lnb,
    const float* __restrict__ gatePtr, float* __restrict__ out)
{
    __shared__ short ot[16 * 776];
    __shared__ float mean_s[16], rsv_s[16];
    int lt = blockIdx.x, b = blockIdx.y;
    int l0 = lt * 16;
    int tid = threadIdx.x;
    int rows = Lc - l0; if (rows > 16) rows = 16;
    const short* src = o + ((long)b * Lc + l0) * Cc;
    int n8 = rows * 96;
    for (int idx = tid; idx < n8; idx += 256) {
        int rr = idx / 96, c8 = idx % 96;
        short8v val = *(const short8v*)(src + (long)rr * Cc + c8 * 8);
        *(short8v*)&ot[rr * 776 + c8 * 8] = val;
    }
    __syncthreads();
    int w = tid >> 6, lane = tid & 63;
    for (int rr = w; rr < rows; rr += 4) {
        float v[12];
        #pragma unroll
        for (int q = 0; q < 3; ++q) {
            int c = lane * 4 + q * 256;
            short4v sv = *(const short4v*)&ot[rr * 776 + c];
            #pragma unroll
            for (int e = 0; e < 4; ++e) v[q * 4 + e] = bf2f(sv[e]);
        }
        float s = 0.f;
        #pragma unroll
        for (int e = 0; e < 12; ++e) s += v[e];
        #pragma unroll
        for (int off = 32; off > 0; off >>= 1) s += __shfl_xor(s, off, 64);
        float mean = s * (1.0f / Cc);
        float var = 0.f;
        #pragma unroll
        for (int e = 0; e < 12; ++e) { float d = v[e] - mean; var += d * d; }
        #pragma unroll
        for (int off = 32; off > 0; off >>= 1) var += __shfl_xor(var, off, 64);
        if (lane == 0) {
            mean_s[rr] = mean;
            rsv_s[rr] = rsqrtf(var * (1.0f / Cc) + EPSc);
        }
    }
    __syncthreads();
    float gate = gatePtr[0];
    if (rows == 16) {
        for (int idx = tid; idx < Cc * 4; idx += 256) {
            int c = idx >> 2, q = idx & 3;
            float lg = lng[c], lb = lnb[c];
            f32x4 val;
            #pragma unroll
            for (int e = 0; e < 4; ++e) {
                int rr = q * 4 + e;
                float xv = bf2f(ot[rr * 776 + c]);
                val[e] = gate * ((xv - mean_s[rr]) * rsv_s[rr] * lg + lb);
            }
            *(f32x4*)(out + ((long)b * Cc + c) * Lc + l0 + q * 4) = val;
        }
    } else {  // rows == 4
        for (int idx = tid; idx < Cc; idx += 256) {
            int c = idx;
            float lg = lng[c], lb = lnb[c];
            f32x4 val;
            #pragma unroll
            for (int e = 0; e < 4; ++e) {
                float xv = bf2f(ot[e * 776 + c]);
                val[e] = gate * ((xv - mean_s[e]) * rsv_s[e] * lg + lb);
            }
            *(f32x4*)(out + ((long)b * Cc + c) * Lc + l0) = val;
        }
    }
}

extern "C" void kernel_launch(void* const* d_in, const int* in_sizes, int n_in,
                              void* d_out, int out_size, void* d_ws, size_t ws_size,
                              hipStream_t stream)
{
    const float* x       = (const float*)d_in[0];
    const float* vis     = (const float*)d_in[1];
    const float* conv_w  = (const float*)d_in[2];
    const float* conv_b  = (const float*)d_in[3];
    const float* fc_w    = (const float*)d_in[4];
    const float* fc_b    = (const float*)d_in[5];
    const float* my_tok  = (const float*)d_in[6];
    const float* gate_av = (const float*)d_in[7];
    const float* a1_w    = (const float*)d_in[8];
    const float* a1_b    = (const float*)d_in[9];
    const float* v1_w    = (const float*)d_in[10];
    const float* v1_b    = (const float*)d_in[11];
    const float* bt_w    = (const float*)d_in[12];
    const float* bt_b    = (const float*)d_in[13];
    const float* vc_w    = (const float*)d_in[14];
    const float* vc_b    = (const float*)d_in[15];
    const float* v2_w    = (const float*)d_in[16];
    const float* v2_b    = (const float*)d_in[17];
    const float* a2_w    = (const float*)d_in[18];
    const float* a2_b    = (const float*)d_in[19];
    const float* vs_w    = (const float*)d_in[20];
    const float* vs_b    = (const float*)d_in[21];
    const float* tg_w    = (const float*)d_in[22];
    const float* tg_b    = (const float*)d_in[23];
    const float* lnb_g   = (const float*)d_in[24];
    const float* lnb_b   = (const float*)d_in[25];
    const float* down_w  = (const float*)d_in[26];
    const float* bn1_g   = (const float*)d_in[27];
    const float* bn1_b   = (const float*)d_in[28];
    const float* bn1_m   = (const float*)d_in[29];
    const float* bn1_v   = (const float*)d_in[30];
    const float* up_w    = (const float*)d_in[31];
    const float* bn2_g   = (const float*)d_in[32];
    const float* bn2_b   = (const float*)d_in[33];
    const float* bn2_m   = (const float*)d_in[34];
    const float* bn2_v   = (const float*)d_in[35];
    const float* lnp_g   = (const float*)d_in[36];
    const float* lnp_b   = (const float*)d_in[37];
    const float* gate    = (const float*)d_in[38];

    float* out = (float*)d_out;
    float* outSpat = out + (long)Bc * Cc * Lc;
    float* outTemp = outSpat + (long)Bc * Lc;

    // ---- f32 workspace ----
    float* wsf   = (float*)d_ws;
    float* scoresf = wsf;                     //  2,729,280
    float* audio = scoresf + 2729280L;        //    122,880  (memset group start)
    float* vq1m  = audio + 122880L;           //    122,880
    float* stmp  = vq1m + 122880L;            //     31,360  (memset group end)
    float* chp1  = stmp + 31360L;             //    122,880
    float* aq2   = chp1 + 122880L;            //     61,440
    float* ssig  = aq2 + 61440L;              //     31,360
    float* tempv = ssig + 31360L;             //        192
    float* bnscl1 = tempv + 192L;             //         64
    float* bnsft1 = bnscl1 + 64L;             //         64
    float* bnscl2 = bnsft1 + 64L;             //        768
    float* bnsft2 = bnscl2 + 768L;            //        768
    // ---- bf16 (short) workspace ----
    short* wss   = (short*)(bnsft2 + 768L);
    short* P2    = wss;                       // 24,084,480 : V -> xt2 -> x6n -> o
    short* P3    = P2 + 24084480L;            // 10,690,560 : h(ld224) -> rep
    short* P4    = P3 + 10690560L;            //  3,118,080 : att(ld224) -> att2(ld96)
    short* zb_bf = P4 + 3118080L;             //  2,007,040
    short* audio_bf = zb_bf + 2007040L;       //    122,880
    short* avqin_bf = audio_bf + 122880L;     //    122,880
    short* avq_bf   = avqin_bf + 122880L;     //     61,440
    short* mytok_bf = avq_bf + 61440L;        //     66,816
    short* wconv = mytok_bf + 66816L;         //    100,352
    short* wa1   = wconv + 100352L;           //    589,824
    short* wv1   = wa1 + 589824L;             //    589,824
    short* wbt   = wv1 + 589824L;             //    294,912
    short* wvc   = wbt + 294912L;             //    294,912
    short* wv2   = wvc + 294912L;             //    294,912
    short* wa2   = wv2 + 294912L;             //    294,912
    short* wdown = wa2 + 294912L;             //     36,864
    short* wfc   = wdown + 36864L;            //    172,032 (pad 196->224)
    short* wup   = wfc + 172032L;             //     49,152 (pad 48->64)
    short* vtbf  = wup + 49152L;              // 16,056,320 : vis in bf16

    dim3 blk(256);
    auto cgrid = [](long n) { return dim3((unsigned)((n + 255) / 256)); };
    const int MF = Bc * Lc;   // 31360 = 245*128 exactly

    // ---- prep ----
    k_cvt_vis<<<dim3(7840), blk, 0, stream>>>(vis, vtbf, 16056320L);
    k_cvt_weights<<<cgrid(2784512L), blk, 0, stream>>>(
        my_tok, conv_w, a1_w, v1_w, bt_w, vc_w, v2_w, a2_w, down_w, fc_w, up_w,
        mytok_bf, wconv, wa1, wv1, wbt, wvc, wv2, wa2, wdown, wfc, wup);
    k_prep<<<1, 768, 0, stream>>>(bn1_g, bn1_b, bn1_m, bn1_v,
                                  bn2_g, bn2_b, bn2_m, bn2_v,
                                  bnscl1, bnsft1, bnscl2, bnsft2);
    hipMemsetAsync(audio, 0, (size_t)(122880 + 122880 + 31360) * sizeof(float), stream);

    // 1. h[b,o,n] (ld 224) = conv_w . vtbf^T + conv_b[o]  (per-batch, DEEP)
    mgemm<1,0,0,2,0,false,false,false,false,0,true,false,true><<<dim3(160*4), blk, 0, stream>>>(
        wconv, 0, vtbf, (long)NVc*Dc, 0, 0, nullptr, 0, P3, (long)NVc*224, 224,
        nullptr, 0, nullptr, 0, nullptr, conv_b, nullptr, nullptr, nullptr, nullptr, nullptr,
        NVc, NVc, Dc, 2, 2, 1.f);

    // 2. V = h . fc_w^T + fc_b (FLAT); audio += rows/NV per batch  [DEEP]
    mgemm<2,0,0,2,0,false,true,false,false,0,false,true,true><<<dim3(245*6), blk, 0, stream>>>(
        P3, 0, wfc, 0, 0, 224, nullptr, 0, P2, 0, Cc,
        audio, Cc, nullptr, 0, nullptr, nullptr, fc_b, nullptr, nullptr, nullptr, nullptr,
        MF, Cc, 224, 245, 6, 1.0f/NVc);

    // 3. audio_bf + temporal
    k_audio_fin<<<dim3(Bc), blk, 0, stream>>>(audio, audio_bf, tg_w, tg_b, tempv, outTemp);

    // 4. S[b,t,n] = my_tok . V^T  (per-batch, f32 store)  [DEEP]
    mgemm<0,0,0,1,0,false,false,false,false,0,true,false,false><<<dim3(160*2), blk, 0, stream>>>(
        mytok_bf, 0, P2, (long)NVc*Cc, 0, Cc, scoresf, (long)Tc*NVc, nullptr, 0, 0,
        nullptr, 0, nullptr, 0, nullptr, nullptr, nullptr, nullptr, nullptr, nullptr, nullptr,
        Tc, NVc, Cc, 1, 2, 1.f);

    // 5. att = softmax_n -> bf16 ld 224
    k_softmax_w<<<dim3((Bc*Tc+3)/4), blk, 0, stream>>>(scoresf, P4, NVc, 224, Bc*Tc);

    // 6. rep[b,t,c] = my_tok + att . V   (NN, K=224, Klim=196, per-batch, T14)
    mgemm<0,0,0,2,1,false,false,false,false,1,true,false,true><<<dim3(160*6), blk, 0, stream>>>(
        P4, (long)Tc*224, P2, (long)NVc*Cc, Cc, NVc, nullptr, 0, P3, (long)Tc*Cc, Cc,
        nullptr, 0, my_tok, 0, nullptr, nullptr, nullptr, nullptr, nullptr, nullptr, nullptr,
        Tc, Cc, 224, 1, 6, 1.f);

    // 7. xt2 = transpose(x) -> bf16 (P2 overwrites V)
    k_transpose<<<dim3(7,12,Bc), blk, 0, stream>>>(x, P2);

    // 8. S2[b,l,t] = xt2 . rep^T  (per-batch, f32 store)  [DEEP]
    mgemm<0,0,0,1,0,false,false,false,false,0,true,false,false><<<dim3(160*2), blk, 0, stream>>>(
        P2, (long)Lc*Cc, P3, (long)Tc*Cc, 0, Cc, scoresf, (long)Lc*Tc, nullptr, 0, 0,
        nullptr, 0, nullptr, 0, nullptr, nullptr, nullptr, nullptr, nullptr, nullptr, nullptr,
        Lc, Tc, Cc, 2, 1, 1.f);

    // 9. att2 = softmax_t -> bf16 ld 96
    k_softmax_w<<<dim3((Bc*Lc+3)/4), blk, 0, stream>>>(scoresf, P4, Tc, 96, Bc*Lc);

    // 10. xt2 += gate_av * att2 . rep  (NN, K=96, Klim=87, per-batch, T14), in-place bf16
    mgemm<0,0,0,2,2,false,false,false,false,1,true,false,true><<<dim3(160*12), blk, 0, stream>>>(
        P4, (long)Lc*96, P3, (long)Tc*Cc, Cc, Tc, nullptr, 0, P2, (long)Lc*Cc, Cc,
        nullptr, 0, P2, (long)Lc*Cc, gate_av, nullptr, nullptr, nullptr, nullptr, nullptr, nullptr,
        Lc, Cc, 96, 2, 6, 1.f);

    // 12. vq1m[b,c] = mean_l relu(xt2 . v1_w^T + v1_b)  — 256x256 big tile
    mgemm_vq1m<<<dim3(123*3), dim3(512), 0, stream>>>(
        P2, wv1, v1_b, vq1m, MF, Cc, Cc, 123, 3, 1.0f/Lc);

    // 11+13. avqin = relu(audio . a1_w^T + a1_b) * vq1m -> bf16  [DEEP]
    mgemm<2,1,0,2,0,false,false,false,true,0,false,false,true><<<dim3(12), blk, 0, stream>>>(
        audio_bf, 0, wa1, 0, 0, Cc, nullptr, 0, avqin_bf, 0, Cc,
        nullptr, 0, nullptr, 0, nullptr, nullptr, a1_b, nullptr, nullptr, nullptr, vq1m,
        Bc, Cc, Cc, 2, 6, 1.f);

    // 14. avq = relu(avqin . bt_w^T + bt_b) -> bf16  [DEEP]
    mgemm<2,1,0,2,0,false,false,false,false,0,false,false,true><<<dim3(6), blk, 0, stream>>>(
        avqin_bf, 0, wbt, 0, 0, Cc, nullptr, 0, avq_bf, 0, DMc,
        nullptr, 0, nullptr, 0, nullptr, nullptr, bt_b, nullptr, nullptr, nullptr, nullptr,
        Bc, DMc, Cc, 2, 3, 1.f);

    // 15. chp1 = 1 + sigmoid(avq . vc_w^T + vc_b)  [DEEP]
    mgemm<2,3,0,1,0,false,false,false,false,0,false,false,false><<<dim3(12), blk, 0, stream>>>(
        avq_bf, 0, wvc, 0, 0, DMc, chp1, 0, nullptr, 0, 0,
        nullptr, 0, nullptr, 0, nullptr, nullptr, vc_b, nullptr, nullptr, nullptr, nullptr,
        Bc, Cc, DMc, 2, 6, 1.f);

    // 16+17. aq2 = relu(audio . a2_w^T + a2_b) * vs_w[j]  [DEEP]
    mgemm<2,1,0,1,0,false,false,true,false,0,false,false,false><<<dim3(6), blk, 0, stream>>>(
        audio_bf, 0, wa2, 0, 0, Cc, aq2, 0, nullptr, 0, 0,
        nullptr, 0, nullptr, 0, nullptr, nullptr, a2_b, nullptr, nullptr, vs_w, nullptr,
        Bc, DMc, Cc, 2, 3, 1.f);

    // 18. stmp[i] = sum_m relu((xt2*chp1) . v2_w^T + v2_b) * aq2[b,m]  (FLAT OUT=2, T14 A-scale)
    mgemm<2,1,2,0,0,true,false,false,false,0,false,true,false><<<dim3(245*3), blk, 0, stream>>>(
        P2, 0, wv2, 0, 0, Cc, stmp, 0, nullptr, 0, 0,
        nullptr, 0, nullptr, 0, nullptr, nullptr, v2_b, chp1, aq2, nullptr, nullptr,
        MF, DMc, Cc, 245, 3, 1.f);

    // 20. ssig + spatial softmax
    k_spatial<<<dim3(Bc), blk, 0, stream>>>(stmp, vs_b, ssig, outSpat);

    // 21. x6n = LN(xt2 * factor), in-place bf16 (P2), wave per row
    k_ln_factor<<<dim3(Bc*Lc/4), blk, 0, stream>>>(
        P2, chp1, ssig, tempv, lnb_g, lnb_b);

    // 22. z = relu(bn1(x6n . down_w^T)) -> bf16 ld 64  (FLAT)  [DEEP]
    mgemm<3,1,0,2,0,false,false,false,false,0,false,true,true><<<dim3(245), blk, 0, stream>>>(
        P2, 0, wdown, 0, 0, Cc, nullptr, 0, zb_bf, 0, 64,
        nullptr, 0, nullptr, 0, nullptr, bnscl1, bnsft1, nullptr, nullptr, nullptr, nullptr,
        MF, DSc, Cc, 245, 1, 1.f);

    // 24. o = bn2(z . up_w^T) -> bf16 (P2)  (FLAT, K=64)  [DEEP]
    mgemm<3,0,0,2,0,false,false,false,false,0,false,true,true><<<dim3(245*6), blk, 0, stream>>>(
        zb_bf, 0, wup, 0, 0, 64, nullptr, 0, P2, 0, Cc,
        nullptr, 0, nullptr, 0, nullptr, bnscl2, bnsft2, nullptr, nullptr, nullptr, nullptr,
        MF, Cc, 64, 245, 6, 1.f);

    // 25. out = gate * LN(o) transposed
    k_final<<<dim3(13,Bc), blk, 0, stream>>>(
        P2, lnp_g, lnp_b, gate, out);
}

// Round 13
// 530.273 us; speedup vs baseline: 1.0207x; 1.0207x over previous
//
#include <hip/hip_runtime.h>
#include <math.h>

#define Bc   160
#define Lc   196
#define Cc   768
#define Dc   512
#define NVc  196
#define Tc   87
#define FRc  10
#define DMc  384
#define DSc  48
#define LROW 196
#define ALPHAc 0.3f
#define BETAc  0.05f
#define GAMMAc 0.05f
#define EPSc   1e-5f

typedef __attribute__((ext_vector_type(8))) short short8v;
typedef __attribute__((ext_vector_type(4))) short short4v;
typedef __attribute__((ext_vector_type(4))) float f32x4;

__device__ __forceinline__ short f2bf(float f) {
    unsigned u = __builtin_bit_cast(unsigned, f);
    u = (u + 0x7FFFu + ((u >> 16) & 1u)) >> 16;
    return (short)u;
}
__device__ __forceinline__ float bf2f(short s) {
    unsigned u = ((unsigned)(unsigned short)s) << 16;
    return __builtin_bit_cast(float, u);
}

__device__ __forceinline__ void gload16(const void* g, void* l) {
    using GP = const __attribute__((address_space(1))) unsigned int*;
    using LP = __attribute__((address_space(3))) unsigned int*;
    __builtin_amdgcn_global_load_lds((GP)(uintptr_t)g, (LP)(uintptr_t)l, 16, 0, 0);
}

// ============================================================
// bf16 MFMA GEMM, 128x128 tile.
// DEEP path (BMODE==0 && !ASCALE): tri-buffered LDS, 2-tiles-ahead prefetch,
//   raw s_barrier + counted s_waitcnt vmcnt(4) (vmcnt(0) only on last step).
// Non-DEEP: T14 async-split reg staging.
// TSTORE: coalesced short8 stores via LDS re-tile.
// ============================================================
template<int BIAS, int ACT, int OUT, int STORE, int ADDT,
         bool ASCALE, bool RSUM, bool CSCALE, bool MULP, int BMODE, bool SWZ, bool FLAT,
         bool TSTORE>
__global__ __launch_bounds__(256) void mgemm(
    const short* __restrict__ A, long sA,
    const void* __restrict__ Bp, long sB, int ldB, int Klim,
    float* __restrict__ Cf, long sCf,
    short* __restrict__ Cb, long sCb, int ldC,
    float* __restrict__ Rf, long sRf,
    const void* __restrict__ Addp, long sAdd,
    const float* __restrict__ scalePtr,
    const float* __restrict__ biasR, const float* __restrict__ biasC,
    const float* __restrict__ ascale, const float* __restrict__ wcol,
    const float* __restrict__ csc, const float* __restrict__ mulp,
    int M, int N, int K, int nI, int nJ, float outScale)
{
    constexpr bool DEEP = (BMODE == 0) && !ASCALE;
    constexpr int LDSN = DEEP ? 24576 : 16384;
    constexpr int BOFF = DEEP ? 12288 : 8192;
    __shared__ short smem[LDSN];
    int b, iT, jT;
    if (FLAT) {
        b = 0;
        int id = blockIdx.x;
        int nI8 = (nI >> 3) << 3;
        int main_ = nI8 * nJ;
        if (id < main_) { int xx = id & 7; int q = id >> 3; jT = q % nJ; iT = (q / nJ) * 8 + xx; }
        else { int id2 = id - main_; iT = nI8 + id2 / nJ; jT = id2 % nJ; }
    } else {
        const int tiles = nI * nJ;
        int t;
        if (SWZ) { int id = blockIdx.x; b = ((id >> 3) / tiles) * 8 + (id & 7); t = (id >> 3) % tiles; }
        else     { int id = blockIdx.x; b = id / tiles; t = id % tiles; }
        iT = t / nJ; jT = t % nJ;
    }
    const int i0 = iT * 128, j0 = jT * 128;
    const int tid = threadIdx.x;
    const int wl = tid & 63, w = tid >> 6;
    const int wr = (w >> 1) * 64, wc = (w & 1) * 64;
    const int lr = wl & 15;
    const int kgl = (((wl >> 4) ^ (lr & 3) ^ ((lr >> 2) & 3)) * 8);
    const int sl8 = (((tid & 3) ^ ((tid >> 2) & 3) ^ ((tid >> 4) & 3)) * 8);
    const int grow = w * 16 + (wl >> 2);
    const int srow = tid >> 2;
    const short* Ab = A + (FLAT ? 0L : (long)b * sA);

    f32x4 acc[4][4] = {};

    auto GLA = [&](short* Asb, int k0) {
        #pragma unroll
        for (int h = 0; h < 2; ++h) {
            int gi = i0 + h * 64 + grow; if (gi > M - 1) gi = M - 1;
            gload16(Ab + (long)gi * K + k0 + sl8, Asb + h * 2048 + w * 512);
        }
    };
    auto GLB = [&](short* Bsb, int k0) {
        const short* Bb = (const short*)Bp + (FLAT ? 0L : (long)b * sB);
        #pragma unroll
        for (int h = 0; h < 2; ++h) {
            int gj = j0 + h * 64 + grow; if (gj > N - 1) gj = N - 1;
            gload16(Bb + (long)gj * K + k0 + sl8, Bsb + h * 2048 + w * 512);
        }
    };
    auto LDA_R = [&](int k0, short8v& a0, short8v& a1) {
        {
            int gi = i0 + srow; if (gi > M - 1) gi = M - 1;
            short8v av = *(const short8v*)(Ab + (long)gi * K + k0 + (tid & 3) * 8);
            int bb = FLAT ? (gi / LROW) : b;
            const float* asb = ascale + (long)bb * K + k0 + (tid & 3) * 8;
            #pragma unroll
            for (int e = 0; e < 8; ++e) av[e] = f2bf(bf2f(av[e]) * asb[e]);
            a0 = av;
        }
        {
            int gi = i0 + srow + 64; if (gi > M - 1) gi = M - 1;
            short8v av = *(const short8v*)(Ab + (long)gi * K + k0 + (tid & 3) * 8);
            int bb = FLAT ? (gi / LROW) : b;
            const float* asb = ascale + (long)bb * K + k0 + (tid & 3) * 8;
            #pragma unroll
            for (int e = 0; e < 8; ++e) av[e] = f2bf(bf2f(av[e]) * asb[e]);
            a1 = av;
        }
    };
    auto WRA_R = [&](short* Asb, short8v a0, short8v a1) {
        *(short8v*)&Asb[srow * 32 + sl8] = a0;
        *(short8v*)&Asb[(srow + 64) * 32 + sl8] = a1;
    };
    auto LDB1_R = [&](int k0, short8v& b0, short8v& b1) {
        const short* Bb = (const short*)Bp + (long)b * sB;
        {
            int kk = tid >> 4, jg = tid & 15;
            int gk = k0 + kk, gj = j0 + jg * 8;
            short8v bv = {};
            if (gk < Klim && gj < N) bv = *(const short8v*)(Bb + (long)gk * ldB + gj);
            b0 = bv;
        }
        {
            int idx = tid + 256;
            int kk = idx >> 4, jg = idx & 15;
            int gk = k0 + kk, gj = j0 + jg * 8;
            short8v bv = {};
            if (gk < Klim && gj < N) bv = *(const short8v*)(Bb + (long)gk * ldB + gj);
            b1 = bv;
        }
    };
    auto WRB1_R = [&](short* Bsb, short8v b0, short8v b1) {
        {
            int kk = tid >> 4, jg = tid & 15;
            #pragma unroll
            for (int e = 0; e < 8; ++e) {
                int row = jg * 8 + e;
                int slot = (kk >> 3) ^ (row & 3) ^ ((row >> 2) & 3);
                Bsb[row * 32 + slot * 8 + (kk & 7)] = b0[e];
            }
        }
        {
            int idx = tid + 256;
            int kk = idx >> 4, jg = idx & 15;
            #pragma unroll
            for (int e = 0; e < 8; ++e) {
                int row = jg * 8 + e;
                int slot = (kk >> 3) ^ (row & 3) ^ ((row >> 2) & 3);
                Bsb[row * 32 + slot * 8 + (kk & 7)] = b1[e];
            }
        }
    };
    auto COMPUTE = [&](const short* as, const short* bs) {
        short8v af[4], bfv[4];
        #pragma unroll
        for (int m = 0; m < 4; ++m) af[m]  = *(const short8v*)&as[(wr + m * 16 + lr) * 32 + kgl];
        #pragma unroll
        for (int n = 0; n < 4; ++n) bfv[n] = *(const short8v*)&bs[(wc + n * 16 + lr) * 32 + kgl];
        #pragma unroll
        for (int m = 0; m < 4; ++m)
            #pragma unroll
            for (int n = 0; n < 4; ++n)
                acc[m][n] = __builtin_amdgcn_mfma_f32_16x16x32_bf16(af[m], bfv[n], acc[m][n], 0, 0, 0);
    };

    const int nt = K >> 5;
    if (DEEP) {
        GLA(smem, 0); GLB(smem + BOFF, 0);
        if (nt > 1) { GLA(smem + 4096, 32); GLB(smem + BOFF + 4096, 32); }
        for (int tt = 0; tt < nt; ++tt) {
            if (tt + 1 < nt) asm volatile("s_waitcnt vmcnt(4)" ::: "memory");
            else             asm volatile("s_waitcnt vmcnt(0)" ::: "memory");
            __builtin_amdgcn_s_barrier();
            __builtin_amdgcn_sched_barrier(0);
            if (tt + 2 < nt) {
                int nb = (tt + 2) % 3;
                GLA(smem + nb * 4096, (tt + 2) * 32);
                GLB(smem + BOFF + nb * 4096, (tt + 2) * 32);
            }
            int cb = tt % 3;
            COMPUTE(smem + cb * 4096, smem + BOFF + cb * 4096);
        }
    } else {
        short8v rA0{}, rA1{}, rB0{}, rB1{};
        if (ASCALE) { LDA_R(0, rA0, rA1); WRA_R(smem, rA0, rA1); }
        else GLA(smem, 0);
        if (BMODE == 1) { LDB1_R(0, rB0, rB1); WRB1_R(smem + BOFF, rB0, rB1); }
        else GLB(smem + BOFF, 0);
        if (nt > 1) {
            if (ASCALE) LDA_R(32, rA0, rA1);
            if (BMODE == 1) LDB1_R(32, rB0, rB1);
        }
        for (int tt = 0; tt < nt; ++tt) {
            __syncthreads();
            if (tt + 1 < nt) {
                short* ab  = smem + ((tt + 1) & 1) * 4096;
                short* bb2 = smem + BOFF + ((tt + 1) & 1) * 4096;
                if (ASCALE) WRA_R(ab, rA0, rA1); else GLA(ab, (tt + 1) * 32);
                if (BMODE == 1) WRB1_R(bb2, rB0, rB1);
                else GLB(bb2, (tt + 1) * 32);
            }
            short8v nA0 = rA0, nA1 = rA1, nB0 = rB0, nB1 = rB1;
            if (tt + 2 < nt) {
                if (ASCALE) LDA_R((tt + 2) * 32, nA0, nA1);
                if (BMODE == 1) LDB1_R((tt + 2) * 32, nB0, nB1);
            }
            COMPUTE(smem + (tt & 1) * 4096, smem + BOFF + (tt & 1) * 4096);
            rA0 = nA0; rA1 = nA1; rB0 = nB0; rB1 = nB1;
        }
    }

    const int colbase = j0 + wc;
    const int rowbase = i0 + wr;
    float scale = 1.f;
    if (ADDT) scale = scalePtr ? scalePtr[0] : 1.f;
    const int bA = FLAT ? (i0 / LROW) : 0;
    const bool straddle = FLAT && (((i0 + 127) / LROW) != bA);

    if (OUT == 0 && TSTORE) {
        float rsum[4] = {0.f, 0.f, 0.f, 0.f};
        float rsum2[4] = {0.f, 0.f, 0.f, 0.f};
        __syncthreads();
        #pragma unroll
        for (int n = 0; n < 4; ++n) {
            int col = wc + n * 16 + lr;
            int j = j0 + col;
            int jc = j < N ? j : N - 1;
            #pragma unroll
            for (int m = 0; m < 4; ++m) {
                #pragma unroll
                for (int r = 0; r < 4; ++r) {
                    int row = wr + m * 16 + (wl >> 4) * 4 + r;
                    int i = i0 + row;
                    int ic = i < M ? i : M - 1;
                    float v = acc[m][n][r];
                    if (BIAS == 1) v += biasR[ic];
                    else if (BIAS == 2) v += biasC[jc];
                    else if (BIAS == 3) v = v * biasR[jc] + biasC[jc];
                    if (ACT == 1) v = fmaxf(v, 0.f);
                    else if (ACT == 2) v = 1.f / (1.f + expf(-v));
                    else if (ACT == 3) v = 1.f + 1.f / (1.f + expf(-v));
                    if (CSCALE) v *= csc[jc];
                    if (MULP) v *= mulp[(long)ic * N + jc];
                    smem[row * 128 + col] = f2bf(v);
                    if (RSUM && j < N && i < M) {
                        if (FLAT && (i / LROW) != bA) rsum2[n] += v;
                        else rsum[n] += v;
                    }
                }
            }
        }
        if (RSUM) {
            #pragma unroll
            for (int n = 0; n < 4; ++n) {
                int j = colbase + n * 16 + lr;
                float s = rsum[n];
                s += __shfl_xor(s, 16, 64);
                s += __shfl_xor(s, 32, 64);
                float s2 = 0.f;
                if (FLAT && straddle) {
                    s2 = rsum2[n];
                    s2 += __shfl_xor(s2, 16, 64);
                    s2 += __shfl_xor(s2, 32, 64);
                }
                if ((wl >> 4) == 0 && j < N) {
                    atomicAdd(&Rf[(long)bA * sRf + (FLAT ? 0 : (long)b * sRf) + j], s * outScale);
                    if (FLAT && straddle)
                        atomicAdd(&Rf[(long)(bA + 1) * sRf + j], s2 * outScale);
                }
            }
        }
        __syncthreads();
        #pragma unroll
        for (int p = 0; p < 8; ++p) {
            int row = (tid >> 4) + p * 16;
            int i = i0 + row;
            int c8 = (tid & 15) * 8;
            int j = j0 + c8;
            if (i < M && j < ldC) {
                short8v sv = *(const short8v*)&smem[row * 128 + c8];
                if (ADDT == 2) {
                    const short* ap = (const short*)Addp + (long)b * sAdd + (long)i * N + j;
                    short8v av = *(const short8v*)ap;
                    #pragma unroll
                    for (int e = 0; e < 8; ++e) sv[e] = f2bf(bf2f(av[e]) + scale * bf2f(sv[e]));
                } else if (ADDT == 1) {
                    const float* ap = (const float*)Addp + (long)b * sAdd + (long)i * N + j;
                    f32x4 lo = *(const f32x4*)ap, hi = *(const f32x4*)(ap + 4);
                    #pragma unroll
                    for (int e = 0; e < 4; ++e) sv[e] = f2bf(lo[e] + scale * bf2f(sv[e]));
                    #pragma unroll
                    for (int e = 0; e < 4; ++e) sv[e + 4] = f2bf(hi[e] + scale * bf2f(sv[e + 4]));
                }
                *(short8v*)&Cb[(long)b * sCb + (long)i * ldC + j] = sv;
            }
        }
    } else if (OUT == 0) {
        float rsum[4] = {0.f, 0.f, 0.f, 0.f};
        float rsum2[4] = {0.f, 0.f, 0.f, 0.f};
        #pragma unroll
        for (int n = 0; n < 4; ++n) {
            int j = colbase + n * 16 + lr;
            if (j >= N) continue;
            #pragma unroll
            for (int m = 0; m < 4; ++m) {
                #pragma unroll
                for (int r = 0; r < 4; ++r) {
                    int i = rowbase + m * 16 + (wl >> 4) * 4 + r;
                    if (i >= M) continue;
                    float v = acc[m][n][r];
                    if (BIAS == 1) v += biasR[i];
                    else if (BIAS == 2) v += biasC[j];
                    else if (BIAS == 3) v = v * biasR[j] + biasC[j];
                    if (ACT == 1) v = fmaxf(v, 0.f);
                    else if (ACT == 2) v = 1.f / (1.f + expf(-v));
                    else if (ACT == 3) v = 1.f + 1.f / (1.f + expf(-v));
                    if (CSCALE) v *= csc[j];
                    if (MULP) v *= mulp[(long)i * N + j];
                    if (ADDT == 1) v = ((const float*)Addp)[(long)b * sAdd + (long)i * N + j] + scale * v;
                    else if (ADDT == 2) v = bf2f(((const short*)Addp)[(long)b * sAdd + (long)i * N + j]) + scale * v;
                    if (STORE & 1) Cf[(long)b * sCf + (long)i * N + j] = v;
                    if (STORE & 2) Cb[(long)b * sCb + (long)i * ldC + j] = f2bf(v);
                    if (RSUM) {
                        if (FLAT && (i / LROW) != bA) rsum2[n] += v;
                        else rsum[n] += v;
                    }
                }
            }
        }
        if (RSUM) {
            #pragma unroll
            for (int n = 0; n < 4; ++n) {
                int j = colbase + n * 16 + lr;
                float s = rsum[n];
                s += __shfl_xor(s, 16, 64);
                s += __shfl_xor(s, 32, 64);
                float s2 = 0.f;
                if (FLAT && straddle) {
                    s2 = rsum2[n];
                    s2 += __shfl_xor(s2, 16, 64);
                    s2 += __shfl_xor(s2, 32, 64);
                }
                if ((wl >> 4) == 0 && j < N) {
                    atomicAdd(&Rf[(long)bA * sRf + (FLAT ? 0 : (long)b * sRf) + j], s * outScale);
                    if (FLAT && straddle)
                        atomicAdd(&Rf[(long)(bA + 1) * sRf + j], s2 * outScale);
                }
            }
        }
    } else if (OUT == 1) {
        #pragma unroll
        for (int n = 0; n < 4; ++n) {
            int j = colbase + n * 16 + lr;
            if (j < N) {
                float s = 0.f, s2 = 0.f;
                #pragma unroll
                for (int m = 0; m < 4; ++m)
                    #pragma unroll
                    for (int r = 0; r < 4; ++r) {
                        int i = rowbase + m * 16 + (wl >> 4) * 4 + r;
                        if (i >= M) continue;
                        float v = acc[m][n][r];
                        if (BIAS == 2) v += biasC[j];
                        if (ACT == 1) v = fmaxf(v, 0.f);
                        if (FLAT && (i / LROW) != bA) s2 += v; else s += v;
                    }
                s += __shfl_xor(s, 16, 64);
                s += __shfl_xor(s, 32, 64);
                if (FLAT && straddle) {
                    s2 += __shfl_xor(s2, 16, 64);
                    s2 += __shfl_xor(s2, 32, 64);
                }
                if ((wl >> 4) == 0) {
                    atomicAdd(&Cf[(long)(FLAT ? bA : b) * sCf + j], s * outScale);
                    if (FLAT && straddle)
                        atomicAdd(&Cf[(long)(bA + 1) * sCf + j], s2 * outScale);
                }
            }
        }
    } else {
        #pragma unroll
        for (int m = 0; m < 4; ++m) {
            #pragma unroll
            for (int r = 0; r < 4; ++r) {
                int i = rowbase + m * 16 + (wl >> 4) * 4 + r;
                int bw = FLAT ? (i < M ? i / LROW : 0) : b;
                float s = 0.f;
                #pragma unroll
                for (int n = 0; n < 4; ++n) {
                    int j = colbase + n * 16 + lr;
                    if (j >= N) continue;
                    float v = acc[m][n][r];
                    if (BIAS == 2) v += biasC[j];
                    if (ACT == 1) v = fmaxf(v, 0.f);
                    s += v * wcol[(long)bw * N + j];
                }
                s += __shfl_xor(s, 1, 64);
                s += __shfl_xor(s, 2, 64);
                s += __shfl_xor(s, 4, 64);
                s += __shfl_xor(s, 8, 64);
                if (lr == 0 && i < M)
                    atomicAdd(&Cf[(FLAT ? (long)i : (long)b * sCf + i)], s * outScale);
            }
        }
    }
}

// ============================================================
// merged prep: vis convert (8/thread) | weights | zero | bn prep
// ============================================================
#define VISBLK 7840
#define WTBLK  10877
#define ZBLK   1083
__global__ __launch_bounds__(256) void k_prepall(
    const float* __restrict__ vis, short* __restrict__ vtbf,
    const float* __restrict__ my_tok, const float* __restrict__ conv_w,
    const float* __restrict__ a1_w, const float* __restrict__ v1_w,
    const float* __restrict__ bt_w, const float* __restrict__ vc_w,
    const float* __restrict__ v2_w, const float* __restrict__ a2_w,
    const float* __restrict__ down_w, const float* __restrict__ fc_w,
    const float* __restrict__ up_w,
    short* __restrict__ mytok_bf, short* __restrict__ wconv,
    short* __restrict__ wa1, short* __restrict__ wv1,
    short* __restrict__ wbt, short* __restrict__ wvc,
    short* __restrict__ wv2, short* __restrict__ wa2,
    short* __restrict__ wdown, short* __restrict__ wfc, short* __restrict__ wup,
    float* __restrict__ zeroBase,
    const float* g1, const float* b1, const float* m1, const float* v1,
    const float* g2, const float* b2, const float* m2, const float* v2,
    float* scl1, float* sft1, float* scl2, float* sft2)
{
    int blk = blockIdx.x;
    if (blk < VISBLK) {
        long i = ((long)blk * 256 + threadIdx.x) * 8;
        if (i >= 16056320L) return;
        f32x4 lo = *(const f32x4*)(vis + i), hi = *(const f32x4*)(vis + i + 4);
        short8v s;
        s[0] = f2bf(lo[0]); s[1] = f2bf(lo[1]); s[2] = f2bf(lo[2]); s[3] = f2bf(lo[3]);
        s[4] = f2bf(hi[0]); s[5] = f2bf(hi[1]); s[6] = f2bf(hi[2]); s[7] = f2bf(hi[3]);
        *(short8v*)(vtbf + i) = s;
        return;
    }
    blk -= VISBLK;
    if (blk < WTBLK) {
        long idx = (long)blk * 256 + threadIdx.x;
        if (idx < 66816)  { mytok_bf[idx] = f2bf(my_tok[idx]); return; }  idx -= 66816;
        if (idx < 100352) { wconv[idx] = f2bf(conv_w[idx]); return; }     idx -= 100352;
        if (idx < 589824) { wa1[idx] = f2bf(a1_w[idx]); return; }         idx -= 589824;
        if (idx < 589824) { wv1[idx] = f2bf(v1_w[idx]); return; }         idx -= 589824;
        if (idx < 294912) { wbt[idx] = f2bf(bt_w[idx]); return; }         idx -= 294912;
        if (idx < 294912) { wvc[idx] = f2bf(vc_w[idx]); return; }         idx -= 294912;
        if (idx < 294912) { wv2[idx] = f2bf(v2_w[idx]); return; }         idx -= 294912;
        if (idx < 294912) { wa2[idx] = f2bf(a2_w[idx]); return; }         idx -= 294912;
        if (idx < 36864)  { wdown[idx] = f2bf(down_w[idx]); return; }     idx -= 36864;
        if (idx < 172032) { int r = (int)(idx / 224), c = (int)(idx % 224);
                            wfc[idx] = (c < 196) ? f2bf(fc_w[(long)r * 196 + c]) : (short)0; return; }
        idx -= 172032;
        if (idx < 49152)  { int r = (int)(idx / 64), c = (int)(idx % 64);
                            wup[idx] = (c < 48) ? f2bf(up_w[(long)r * 48 + c]) : (short)0; }
        return;
    }
    blk -= WTBLK;
    if (blk < ZBLK) {
        long idx = (long)blk * 256 + threadIdx.x;
        if (idx < 277120L) zeroBase[idx] = 0.f;
        return;
    }
    // bn prep (one block of 256 threads; FIX: stride loop covers all 768)
    int j = threadIdx.x;
    if (j < DSc) { float r = rsqrtf(v1[j] + EPSc) * g1[j]; scl1[j] = r; sft1[j] = b1[j] - m1[j] * r; }
    for (int c = j; c < Cc; c += 256) {
        float r = rsqrtf(v2[c] + EPSc) * g2[c];
        scl2[c] = r; sft2[c] = b2[c] - m2[c] * r;
    }
}

// xt[b,l,c] = x[b,c,l] -> bf16, 64c x 32l tile, short4 stores
__global__ __launch_bounds__(256) void k_transpose(const float* __restrict__ x, short* __restrict__ xtb)
{
    __shared__ float tile[64][33];
    int b = blockIdx.z;
    int c0 = blockIdx.y * 64, l0 = blockIdx.x * 32;
    int tx = threadIdx.x & 31, ty = threadIdx.x >> 5;
    #pragma unroll
    for (int k = 0; k < 8; ++k) {
        int c = c0 + ty + 8 * k, l = l0 + tx;
        tile[ty + 8 * k][tx] = (l < Lc) ? x[((long)b * Cc + c) * Lc + l] : 0.f;
    }
    __syncthreads();
    int cg = threadIdx.x & 15, lw = threadIdx.x >> 4;
    #pragma unroll
    for (int p = 0; p < 2; ++p) {
        int l = l0 + lw + p * 16;
        if (l >= Lc) continue;
        int c = c0 + cg * 4;
        short4v sv;
        #pragma unroll
        for (int e = 0; e < 4; ++e) sv[e] = f2bf(tile[cg * 4 + e][lw + p * 16]);
        *(short4v*)(xtb + ((long)b * Lc + l) * Cc + c) = sv;
    }
}

// audio_bf + temporal gate, one block per b
__global__ __launch_bounds__(256) void k_audio_fin(
    const float* __restrict__ audio, short* __restrict__ audio_bf,
    const float* __restrict__ tg_w, const float* __restrict__ tg_b,
    float* __restrict__ tempv, float* __restrict__ outTemp)
{
    __shared__ float red[256];
    int b = blockIdx.x, tid = threadIdx.x;
    float part = 0.f;
    #pragma unroll
    for (int q = 0; q < 3; ++q) {
        int c = tid + q * 256;
        float a = audio[(long)b * Cc + c];
        audio_bf[(long)b * Cc + c] = f2bf(a);
        part += a * tg_w[c];
    }
    red[tid] = part; __syncthreads();
    for (int s = 128; s > 0; s >>= 1) { if (tid < s) red[tid] += red[tid + s]; __syncthreads(); }
    if (tid == 0) {
        float t = 1.f / (1.f + expf(-(red[0] + tg_b[0])));
        tempv[b] = t; outTemp[b] = t;
    }
}

// wave-per-row softmax: f32 rows (ld n) -> bf16 rows (ld ldo, zero pad)
__global__ __launch_bounds__(256) void k_softmax_w(const float* __restrict__ in,
                                                   short* __restrict__ out,
                                                   int n, int ldo, int rows)
{
    int r = blockIdx.x * 4 + (threadIdx.x >> 6);
    int lane = threadIdx.x & 63;
    if (r >= rows) return;
    const float* row = in + (long)r * n;
    float v[4];
    float mx = -INFINITY;
    #pragma unroll
    for (int q = 0; q < 4; ++q) {
        int c = lane + q * 64;
        v[q] = (c < n) ? row[c] : -INFINITY;
        mx = fmaxf(mx, v[q]);
    }
    #pragma unroll
    for (int off = 32; off > 0; off >>= 1) mx = fmaxf(mx, __shfl_xor(mx, off, 64));
    float sum = 0.f;
    #pragma unroll
    for (int q = 0; q < 4; ++q) {
        int c = lane + q * 64;
        float e = (c < n) ? expf(v[q] - mx) : 0.f;
        v[q] = e; sum += e;
    }
    #pragma unroll
    for (int off = 32; off > 0; off >>= 1) sum += __shfl_xor(sum, off, 64);
    float inv = 1.0f / sum;
    #pragma unroll
    for (int q = 0; q < 4; ++q) {
        int c = lane + q * 64;
        if (c < ldo) out[(long)r * ldo + c] = (c < n) ? f2bf(v[q] * inv) : (short)0;
    }
}

__global__ __launch_bounds__(256) void k_spatial(const float* __restrict__ stmp,
                                                 const float* __restrict__ vs_b,
                                                 float* __restrict__ ssig,
                                                 float* __restrict__ spat)
{
    __shared__ float red[256];
    int b = blockIdx.x, tid = threadIdx.x;
    float t = -INFINITY;
    if (tid < Lc) {
        float v = stmp[(long)b * Lc + tid] + vs_b[0];
        ssig[(long)b * Lc + tid] = 1.f / (1.f + expf(-v));
        t = tanhf(v);
    }
    red[tid] = t; __syncthreads();
    for (int s = 128; s > 0; s >>= 1) { if (tid < s) red[tid] = fmaxf(red[tid], red[tid + s]); __syncthreads(); }
    float mx = red[0]; __syncthreads();
    float e = (tid < Lc) ? expf(t - mx) : 0.f;
    red[tid] = e; __syncthreads();
    for (int s = 128; s > 0; s >>= 1) { if (tid < s) red[tid] += red[tid + s]; __syncthreads(); }
    if (tid < Lc) spat[(long)b * Lc + tid] = e / red[0];
}

// x6 = LN( bf16(xt) * factor ) -> bf16, in place; one wave per row
__global__ __launch_bounds__(256) void k_ln_factor(
    short* __restrict__ xt, const float* __restrict__ chp1,
    const float* __restrict__ ssig, const float* __restrict__ tmp_,
    const float* __restrict__ g, const float* __restrict__ be)
{
    long r = (long)blockIdx.x * 4 + (threadIdx.x >> 6);
    int lane = threadIdx.x & 63;
    int b = (int)(r / Lc);
    float rowterm = BETAc * ssig[r] + GAMMAc * tmp_[b] + (1.0f - ALPHAc);
    float v[12];
    #pragma unroll
    for (int q = 0; q < 3; ++q) {
        int c = lane * 4 + q * 256;
        short4v sv = *(const short4v*)(xt + r * Cc + c);
        f32x4 ch = *(const f32x4*)(chp1 + (long)b * Cc + c);
        #pragma unroll
        for (int e = 0; e < 4; ++e)
            v[q * 4 + e] = bf2f(sv[e]) * (ALPHAc * (ch[e] - 1.0f) + rowterm);
    }
    float s = 0.f;
    #pragma unroll
    for (int e = 0; e < 12; ++e) s += v[e];
    #pragma unroll
    for (int off = 32; off > 0; off >>= 1) s += __shfl_xor(s, off, 64);
    float mean = s * (1.0f / Cc);
    float var = 0.f;
    #pragma unroll
    for (int e = 0; e < 12; ++e) { float d = v[e] - mean; var += d * d; }
    #pragma unroll
    for (int off = 32; off > 0; off >>= 1) var += __shfl_xor(var, off, 64);
    float rs = rsqrtf(var * (1.0f / Cc) + EPSc);
    #pragma unroll
    for (int q = 0; q < 3; ++q) {
        int c = lane * 4 + q * 256;
        f32x4 gv = *(const f32x4*)(g + c);
        f32x4 bv = *(const f32x4*)(be + c);
        short4v sv;
        #pragma unroll
        for (int e = 0; e < 4; ++e)
            sv[e] = f2bf((v[q * 4 + e] - mean) * rs * gv[e] + bv[e]);
        *(short4v*)(xt + r * Cc + c) = sv;
    }
}

// LN(lnp) -> *gate -> transposed store out[b,c,l]; bf16 LDS tile, wave stats
__global__ __launch_bounds__(256) void k_final(
    const short* __restrict__ o,
    const float* __restrict__ lng, const float* __restrict__ lnb,
    const float* __restrict__ gatePtr, float* __restrict__ out)
{
    __shared__ short ot[16 * 776];
    __shared__ float mean_s[16], rsv_s[16];
    int lt = blockIdx.x, b = blockIdx.y;
    int l0 = lt * 16;
    int tid = threadIdx.x;
    int rows = Lc - l0; if (rows > 16) rows = 16;
    const short* src = o + ((long)b * Lc + l0) * Cc;
    int n8 = rows * 96;
    for (int idx = tid; idx < n8; idx += 256) {
        int rr = idx / 96, c8 = idx % 96;
        short8v val = *(const short8v*)(src + (long)rr * Cc + c8 * 8);
        *(short8v*)&ot[rr * 776 + c8 * 8] = val;
    }
    __syncthreads();
    int w = tid >> 6, lane = tid & 63;
    for (int rr = w; rr < rows; rr += 4) {
        float v[12];
        #pragma unroll
        for (int q = 0; q < 3; ++q) {
            int c = lane * 4 + q * 256;
            short4v sv = *(const short4v*)&ot[rr * 776 + c];
            #pragma unroll
            for (int e = 0; e < 4; ++e) v[q * 4 + e] = bf2f(sv[e]);
        }
        float s = 0.f;
        #pragma unroll
        for (int e = 0; e < 12; ++e) s += v[e];
        #pragma unroll
        for (int off = 32; off > 0; off >>= 1) s += __shfl_xor(s, off, 64);
        float mean = s * (1.0f / Cc);
        float var = 0.f;
        #pragma unroll
        for (int e = 0; e < 12; ++e) { float d = v[e] - mean; var += d * d; }
        #pragma unroll
        for (int off = 32; off > 0; off >>= 1) var += __shfl_xor(var, off, 64);
        if (lane == 0) {
            mean_s[rr] = mean;
            rsv_s[rr] = rsqrtf(var * (1.0f / Cc) + EPSc);
        }
    }
    __syncthreads();
    float gate = gatePtr[0];
    if (rows == 16) {
        for (int idx = tid; idx < Cc * 4; idx += 256) {
            int c = idx >> 2, q = idx & 3;
            float lg = lng[c], lb = lnb[c];
            f32x4 val;
            #pragma unroll
            for (int e = 0; e < 4; ++e) {
                int rr = q * 4 + e;
                float xv = bf2f(ot[rr * 776 + c]);
                val[e] = gate * ((xv - mean_s[rr]) * rsv_s[rr] * lg + lb);
            }
            *(f32x4*)(out + ((long)b * Cc + c) * Lc + l0 + q * 4) = val;
        }
    } else {
        for (int idx = tid; idx < Cc; idx += 256) {
            int c = idx;
            float lg = lng[c], lb = lnb[c];
            f32x4 val;
            #pragma unroll
            for (int e = 0; e < 4; ++e) {
                float xv = bf2f(ot[e * 776 + c]);
                val[e] = gate * ((xv - mean_s[e]) * rsv_s[e] * lg + lb);
            }
            *(f32x4*)(out + ((long)b * Cc + c) * Lc + l0) = val;
        }
    }
}

extern "C" void kernel_launch(void* const* d_in, const int* in_sizes, int n_in,
                              void* d_out, int out_size, void* d_ws, size_t ws_size,
                              hipStream_t stream)
{
    const float* x       = (const float*)d_in[0];
    const float* vis     = (const float*)d_in[1];
    const float* conv_w  = (const float*)d_in[2];
    const float* conv_b  = (const float*)d_in[3];
    const float* fc_w    = (const float*)d_in[4];
    const float* fc_b    = (const float*)d_in[5];
    const float* my_tok  = (const float*)d_in[6];
    const float* gate_av = (const float*)d_in[7];
    const float* a1_w    = (const float*)d_in[8];
    const float* a1_b    = (const float*)d_in[9];
    const float* v1_w    = (const float*)d_in[10];
    const float* v1_b    = (const float*)d_in[11];
    const float* bt_w    = (const float*)d_in[12];
    const float* bt_b    = (const float*)d_in[13];
    const float* vc_w    = (const float*)d_in[14];
    const float* vc_b    = (const float*)d_in[15];
    const float* v2_w    = (const float*)d_in[16];
    const float* v2_b    = (const float*)d_in[17];
    const float* a2_w    = (const float*)d_in[18];
    const float* a2_b    = (const float*)d_in[19];
    const float* vs_w    = (const float*)d_in[20];
    const float* vs_b    = (const float*)d_in[21];
    const float* tg_w    = (const float*)d_in[22];
    const float* tg_b    = (const float*)d_in[23];
    const float* lnb_g   = (const float*)d_in[24];
    const float* lnb_b   = (const float*)d_in[25];
    const float* down_w  = (const float*)d_in[26];
    const float* bn1_g   = (const float*)d_in[27];
    const float* bn1_b   = (const float*)d_in[28];
    const float* bn1_m   = (const float*)d_in[29];
    const float* bn1_v   = (const float*)d_in[30];
    const float* up_w    = (const float*)d_in[31];
    const float* bn2_g   = (const float*)d_in[32];
    const float* bn2_b   = (const float*)d_in[33];
    const float* bn2_m   = (const float*)d_in[34];
    const float* bn2_v   = (const float*)d_in[35];
    const float* lnp_g   = (const float*)d_in[36];
    const float* lnp_b   = (const float*)d_in[37];
    const float* gate    = (const float*)d_in[38];

    float* out = (float*)d_out;
    float* outSpat = out + (long)Bc * Cc * Lc;
    float* outTemp = outSpat + (long)Bc * Lc;

    // ---- f32 workspace ----
    float* wsf   = (float*)d_ws;
    float* scoresf = wsf;                     //  2,729,280
    float* audio = scoresf + 2729280L;        //    122,880  (zero group start)
    float* vq1m  = audio + 122880L;           //    122,880
    float* stmp  = vq1m + 122880L;            //     31,360  (zero group end: 277,120)
    float* chp1  = stmp + 31360L;             //    122,880
    float* aq2   = chp1 + 122880L;            //     61,440
    float* ssig  = aq2 + 61440L;              //     31,360
    float* tempv = ssig + 31360L;             //        192
    float* bnscl1 = tempv + 192L;             //         64
    float* bnsft1 = bnscl1 + 64L;             //         64
    float* bnscl2 = bnsft1 + 64L;             //        768
    float* bnsft2 = bnscl2 + 768L;            //        768
    // ---- bf16 (short) workspace ----
    short* wss   = (short*)(bnsft2 + 768L);
    short* P2    = wss;                       // 24,084,480 : V -> xt2 -> x6n -> o
    short* P3    = P2 + 24084480L;            // 10,690,560 : h(ld224) -> rep
    short* P4    = P3 + 10690560L;            //  3,118,080 : att(ld224) -> att2(ld96)
    short* zb_bf = P4 + 3118080L;             //  2,007,040
    short* audio_bf = zb_bf + 2007040L;       //    122,880
    short* avqin_bf = audio_bf + 122880L;     //    122,880
    short* avq_bf   = avqin_bf + 122880L;     //     61,440
    short* mytok_bf = avq_bf + 61440L;        //     66,816
    short* wconv = mytok_bf + 66816L;         //    100,352
    short* wa1   = wconv + 100352L;           //    589,824
    short* wv1   = wa1 + 589824L;             //    589,824
    short* wbt   = wv1 + 589824L;             //    294,912
    short* wvc   = wbt + 294912L;             //    294,912
    short* wv2   = wvc + 294912L;             //    294,912
    short* wa2   = wv2 + 294912L;             //    294,912
    short* wdown = wa2 + 294912L;             //     36,864
    short* wfc   = wdown + 36864L;            //    172,032 (pad 196->224)
    short* wup   = wfc + 172032L;             //     49,152 (pad 48->64)
    short* vtbf  = wup + 49152L;              // 16,056,320 : vis in bf16

    dim3 blk(256);
    const int MF = Bc * Lc;   // 31360 = 245*128 exactly

    // ---- merged prep (vis cvt | weights | zero | bn prep) ----
    k_prepall<<<dim3(VISBLK + WTBLK + ZBLK + 1), blk, 0, stream>>>(
        vis, vtbf,
        my_tok, conv_w, a1_w, v1_w, bt_w, vc_w, v2_w, a2_w, down_w, fc_w, up_w,
        mytok_bf, wconv, wa1, wv1, wbt, wvc, wv2, wa2, wdown, wfc, wup,
        audio,
        bn1_g, bn1_b, bn1_m, bn1_v, bn2_g, bn2_b, bn2_m, bn2_v,
        bnscl1, bnsft1, bnscl2, bnsft2);

    // 1. h[b,o,n] (ld 224) = conv_w . vtbf^T + conv_b[o]  (per-batch, DEEP)
    mgemm<1,0,0,2,0,false,false,false,false,0,true,false,true><<<dim3(160*4), blk, 0, stream>>>(
        wconv, 0, vtbf, (long)NVc*Dc, 0, 0, nullptr, 0, P3, (long)NVc*224, 224,
        nullptr, 0, nullptr, 0, nullptr, conv_b, nullptr, nullptr, nullptr, nullptr, nullptr,
        NVc, NVc, Dc, 2, 2, 1.f);

    // 2. V = h . fc_w^T + fc_b (FLAT); audio += rows/NV per batch  [DEEP]
    mgemm<2,0,0,2,0,false,true,false,false,0,false,true,true><<<dim3(245*6), blk, 0, stream>>>(
        P3, 0, wfc, 0, 0, 224, nullptr, 0, P2, 0, Cc,
        audio, Cc, nullptr, 0, nullptr, nullptr, fc_b, nullptr, nullptr, nullptr, nullptr,
        MF, Cc, 224, 245, 6, 1.0f/NVc);

    // 3. audio_bf + temporal
    k_audio_fin<<<dim3(Bc), blk, 0, stream>>>(audio, audio_bf, tg_w, tg_b, tempv, outTemp);

    // 4. S[b,t,n] = my_tok . V^T  (per-batch, f32 store)  [DEEP]
    mgemm<0,0,0,1,0,false,false,false,false,0,true,false,false><<<dim3(160*2), blk, 0, stream>>>(
        mytok_bf, 0, P2, (long)NVc*Cc, 0, Cc, scoresf, (long)Tc*NVc, nullptr, 0, 0,
        nullptr, 0, nullptr, 0, nullptr, nullptr, nullptr, nullptr, nullptr, nullptr, nullptr,
        Tc, NVc, Cc, 1, 2, 1.f);

    // 5. att = softmax_n -> bf16 ld 224
    k_softmax_w<<<dim3((Bc*Tc+3)/4), blk, 0, stream>>>(scoresf, P4, NVc, 224, Bc*Tc);

    // 6. rep[b,t,c] = my_tok + att . V   (NN, K=224, Klim=196, per-batch, T14)
    mgemm<0,0,0,2,1,false,false,false,false,1,true,false,true><<<dim3(160*6), blk, 0, stream>>>(
        P4, (long)Tc*224, P2, (long)NVc*Cc, Cc, NVc, nullptr, 0, P3, (long)Tc*Cc, Cc,
        nullptr, 0, my_tok, 0, nullptr, nullptr, nullptr, nullptr, nullptr, nullptr, nullptr,
        Tc, Cc, 224, 1, 6, 1.f);

    // 7. xt2 = transpose(x) -> bf16 (P2 overwrites V)
    k_transpose<<<dim3(7,12,Bc), blk, 0, stream>>>(x, P2);

    // 8. S2[b,l,t] = xt2 . rep^T  (per-batch, f32 store)  [DEEP]
    mgemm<0,0,0,1,0,false,false,false,false,0,true,false,false><<<dim3(160*2), blk, 0, stream>>>(
        P2, (long)Lc*Cc, P3, (long)Tc*Cc, 0, Cc, scoresf, (long)Lc*Tc, nullptr, 0, 0,
        nullptr, 0, nullptr, 0, nullptr, nullptr, nullptr, nullptr, nullptr, nullptr, nullptr,
        Lc, Tc, Cc, 2, 1, 1.f);

    // 9. att2 = softmax_t -> bf16 ld 96
    k_softmax_w<<<dim3((Bc*Lc+3)/4), blk, 0, stream>>>(scoresf, P4, Tc, 96, Bc*Lc);

    // 10. xt2 += gate_av * att2 . rep  (NN, K=96, Klim=87, per-batch, T14), in-place bf16
    mgemm<0,0,0,2,2,false,false,false,false,1,true,false,true><<<dim3(160*12), blk, 0, stream>>>(
        P4, (long)Lc*96, P3, (long)Tc*Cc, Cc, Tc, nullptr, 0, P2, (long)Lc*Cc, Cc,
        nullptr, 0, P2, (long)Lc*Cc, gate_av, nullptr, nullptr, nullptr, nullptr, nullptr, nullptr,
        Lc, Cc, 96, 2, 6, 1.f);

    // 12. vq1m[b,c] = mean_l relu(xt2 . v1_w^T + v1_b)  (FLAT OUT=1)  [DEEP]
    mgemm<2,1,1,0,0,false,false,false,false,0,false,true,false><<<dim3(245*6), blk, 0, stream>>>(
        P2, 0, wv1, 0, 0, Cc, vq1m, Cc, nullptr, 0, 0,
        nullptr, 0, nullptr, 0, nullptr, nullptr, v1_b, nullptr, nullptr, nullptr, nullptr,
        MF, Cc, Cc, 245, 6, 1.0f/Lc);

    // 11+13. avqin = relu(audio . a1_w^T + a1_b) * vq1m -> bf16  [DEEP]
    mgemm<2,1,0,2,0,false,false,false,true,0,false,false,true><<<dim3(12), blk, 0, stream>>>(
        audio_bf, 0, wa1, 0, 0, Cc, nullptr, 0, avqin_bf, 0, Cc,
        nullptr, 0, nullptr, 0, nullptr, nullptr, a1_b, nullptr, nullptr, nullptr, vq1m,
        Bc, Cc, Cc, 2, 6, 1.f);

    // 14. avq = relu(avqin . bt_w^T + bt_b) -> bf16  [DEEP]
    mgemm<2,1,0,2,0,false,false,false,false,0,false,false,true><<<dim3(6), blk, 0, stream>>>(
        avqin_bf, 0, wbt, 0, 0, Cc, nullptr, 0, avq_bf, 0, DMc,
        nullptr, 0, nullptr, 0, nullptr, nullptr, bt_b, nullptr, nullptr, nullptr, nullptr,
        Bc, DMc, Cc, 2, 3, 1.f);

    // 15. chp1 = 1 + sigmoid(avq . vc_w^T + vc_b)  [DEEP]
    mgemm<2,3,0,1,0,false,false,false,false,0,false,false,false><<<dim3(12), blk, 0, stream>>>(
        avq_bf, 0, wvc, 0, 0, DMc, chp1, 0, nullptr, 0, 0,
        nullptr, 0, nullptr, 0, nullptr, nullptr, vc_b, nullptr, nullptr, nullptr, nullptr,
        Bc, Cc, DMc, 2, 6, 1.f);

    // 16+17. aq2 = relu(audio . a2_w^T + a2_b) * vs_w[j]  [DEEP]
    mgemm<2,1,0,1,0,false,false,true,false,0,false,false,false><<<dim3(6), blk, 0, stream>>>(
        audio_bf, 0, wa2, 0, 0, Cc, aq2, 0, nullptr, 0, 0,
        nullptr, 0, nullptr, 0, nullptr, nullptr, a2_b, nullptr, nullptr, vs_w, nullptr,
        Bc, DMc, Cc, 2, 3, 1.f);

    // 18. stmp[i] = sum_m relu((xt2*chp1) . v2_w^T + v2_b) * aq2[b,m]  (FLAT OUT=2, T14 A-scale)
    mgemm<2,1,2,0,0,true,false,false,false,0,false,true,false><<<dim3(245*3), blk, 0, stream>>>(
        P2, 0, wv2, 0, 0, Cc, stmp, 0, nullptr, 0, 0,
        nullptr, 0, nullptr, 0, nullptr, nullptr, v2_b, chp1, aq2, nullptr, nullptr,
        MF, DMc, Cc, 245, 3, 1.f);

    // 20. ssig + spatial softmax
    k_spatial<<<dim3(Bc), blk, 0, stream>>>(stmp, vs_b, ssig, outSpat);

    // 21. x6n = LN(xt2 * factor), in-place bf16 (P2), wave per row
    k_ln_factor<<<dim3(Bc*Lc/4), blk, 0, stream>>>(
        P2, chp1, ssig, tempv, lnb_g, lnb_b);

    // 22. z = relu(bn1(x6n . down_w^T)) -> bf16 ld 64  (FLAT)  [DEEP]
    mgemm<3,1,0,2,0,false,false,false,false,0,false,true,true><<<dim3(245), blk, 0, stream>>>(
        P2, 0, wdown, 0, 0, Cc, nullptr, 0, zb_bf, 0, 64,
        nullptr, 0, nullptr, 0, nullptr, bnscl1, bnsft1, nullptr, nullptr, nullptr, nullptr,
        MF, DSc, Cc, 245, 1, 1.f);

    // 24. o = bn2(z . up_w^T) -> bf16 (P2)  (FLAT, K=64)  [DEEP]
    mgemm<3,0,0,2,0,false,false,false,false,0,false,true,true><<<dim3(245*6), blk, 0, stream>>>(
        zb_bf, 0, wup, 0, 0, 64, nullptr, 0, P2, 0, Cc,
        nullptr, 0, nullptr, 0, nullptr, bnscl2, bnsft2, nullptr, nullptr, nullptr, nullptr,
        MF, Cc, 64, 245, 6, 1.f);

    // 25. out = gate * LN(o) transposed
    k_final<<<dim3(13,Bc), blk, 0, stream>>>(
        P2, lnp_g, lnp_b, gate, out);
}